// Round 5
// baseline (271.359 us; speedup 1.0000x reference)
//
#include <hip/hip_runtime.h>
#include <hip/hip_bf16.h>
#include <cstdint>

#define NPIX 16384   // h*w = 128*128
#define BATCH 8
#define CDIM 256
#define MQKV 768

typedef __bf16 bh8 __attribute__((ext_vector_type(8)));
typedef __bf16 bh4 __attribute__((ext_vector_type(4)));
typedef float  fx4 __attribute__((ext_vector_type(4)));

__device__ __forceinline__ void gload16(const void* g, void* l) {
  __builtin_amdgcn_global_load_lds(
      (const __attribute__((address_space(1))) uint32_t*)g,
      (__attribute__((address_space(3))) uint32_t*)l, 16, 0, 0);
}

__device__ __forceinline__ fx4 mfma16(bh8 a, bh8 b, fx4 c) {
  return __builtin_amdgcn_mfma_f32_16x16x32_bf16(a, b, c, 0, 0, 0);
}

__device__ __forceinline__ void pbar() {
  asm volatile("" ::: "memory");
  __builtin_amdgcn_s_barrier();
  asm volatile("" ::: "memory");
}
#define VMWI(n) asm volatile("s_waitcnt vmcnt(" #n ")" ::: "memory")

// ---------------- pass 0a: convert w_qkv f32 -> bf16 (row-major [768][256]) --
__global__ void conv_w(const float* __restrict__ w, __bf16* __restrict__ wb, int n) {
  int i = blockIdx.x * 256 + threadIdx.x;
  if (i < n) wb[i] = (__bf16)w[i];
}

// ---------------- pass 0b: x [b][256][NPIX] f32 -> xT [b][NPIX][256] bf16 ----
__global__ __launch_bounds__(256) void transpose_x(const float* __restrict__ x,
                                                   __bf16* __restrict__ xT) {
  __shared__ float tile[32][33];
  const int n0 = blockIdx.x * 32, c0 = blockIdx.y * 32, b = blockIdx.z;
  const int tx = threadIdx.x & 31, ty = threadIdx.x >> 5;
#pragma unroll
  for (int j = 0; j < 4; ++j) {
    int r = ty * 4 + j;  // local c
    tile[r][tx] = x[((size_t)b * CDIM + c0 + r) * NPIX + n0 + tx];
  }
  __syncthreads();
#pragma unroll
  for (int j = 0; j < 4; ++j) {
    int nl = ty * 4 + j; // local n
    xT[((size_t)b * NPIX + n0 + nl) * CDIM + c0 + tx] = (__bf16)tile[tx][nl];
  }
}

// ====== 256x128 tile GEMM, K=256 as 4 x BK=64 (r3-proven schedule) ==========
// A single-buffered (32KB), B double-buffered (2x16KB). Staging via
// global_load_lds, conflict-free chunk-XOR swizzle (16B chunk c of row r
// stored at c ^ (r&7); source pre-swizzled). Counted vmcnt(2) per step.
// Epilogue: LDS-bounce per m-slice -> full-cacheline coalesced writes.

#define STA(kt)                                                                \
  do {                                                                         \
    _Pragma("unroll") for (int i_ = 0; i_ < 4; ++i_) {                         \
      int j_ = i_ * 512 + tid;                                                 \
      int row_ = j_ >> 3, c_ = j_ & 7;                                         \
      int sc_ = c_ ^ (row_ & 7);                                               \
      gload16(Ab + (size_t)row_ * 256 + (kt)*64 + sc_ * 8, As + j_ * 8);       \
    }                                                                          \
  } while (0)

#define BSP(pb) ((__bf16*)(smem + 32768 + (pb)*16384))

#define STB(kt, pb)                                                            \
  do {                                                                         \
    _Pragma("unroll") for (int i_ = 0; i_ < 2; ++i_) {                         \
      int j_ = i_ * 512 + tid;                                                 \
      int row_ = j_ >> 3, c_ = j_ & 7;                                         \
      int sc_ = c_ ^ (row_ & 7);                                               \
      gload16(Bb + (size_t)row_ * 256 + (kt)*64 + sc_ * 8, BSP(pb) + j_ * 8);  \
    }                                                                          \
  } while (0)

#define COMP(pb)                                                               \
  do {                                                                         \
    _Pragma("unroll") for (int ks_ = 0; ks_ < 2; ++ks_) {                      \
      bh8 a_[4], b_[4];                                                        \
      const int swk_ = (ks_ * 4 + fq) ^ (fr & 7);                              \
      _Pragma("unroll") for (int m_ = 0; m_ < 4; ++m_)                         \
        a_[m_] = *(const bh8*)&As[(wm * 64 + m_ * 16 + fr) * 64 + swk_ * 8];   \
      _Pragma("unroll") for (int n_ = 0; n_ < 4; ++n_)                         \
        b_[n_] = *(const bh8*)&BSP(pb)[(wn * 64 + n_ * 16 + fr) * 64 + swk_ * 8];\
      _Pragma("unroll") for (int m_ = 0; m_ < 4; ++m_)                         \
      _Pragma("unroll") for (int n_ = 0; n_ < 4; ++n_)                         \
        acc[m_][n_] = mfma16(a_[m_], b_[n_], acc[m_][n_]);                     \
    }                                                                          \
  } while (0)

// EPI==0: A = wqkv rows 256..767 (by=0 -> k with exp(), by=1 -> v)
// EPI==1: A = W3[b]; writes f32 out + bias
template <int EPI>
__global__ __launch_bounds__(512, 4) void gemm256(
    const __bf16* __restrict__ A, const __bf16* __restrict__ Bx,
    __bf16* __restrict__ ekmat, __bf16* __restrict__ vmat,
    const float* __restrict__ bias, float* __restrict__ fout) {
  __shared__ __align__(16) char smem[65536];
  __bf16* As = (__bf16*)smem;       // [256 rows][64 k] 32KB
  const int tid = threadIdx.x;
  const int bx = blockIdx.x, by = blockIdx.y, b = blockIdx.z;
  const int lane = tid & 63, wid = tid >> 6;
  const int wm = wid >> 1, wn = wid & 1;
  const int fr = lane & 15, fq = lane >> 4;
  const __bf16* Ab = A + (size_t)((EPI == 0) ? (1 + by) : b) * 65536;
  const __bf16* Bb = Bx + ((size_t)b * NPIX + (size_t)bx * 128) * 256;

  fx4 acc[4][4] = {};

  STB(0, 0); STA(0);
  STB(1, 1); VMWI(2); pbar(); COMP(0); pbar(); STA(1);
  STB(2, 0); VMWI(2); pbar(); COMP(1); pbar(); STA(2);
  STB(3, 1); VMWI(2); pbar(); COMP(0); pbar(); STA(3);
             VMWI(0); pbar(); COMP(1); pbar();

  // ---- epilogue: per m-slice LDS bounce -> full-line coalesced writes
  if (EPI == 0) {
    __bf16* dst = (by == 0) ? ekmat : vmat;
    const size_t dbase = (size_t)b * CDIM * NPIX + (size_t)bx * 128;
    __bf16* Lh = (__bf16*)smem;     // [64][136] pad: 272B rows, 16B aligned
#pragma unroll
    for (int m = 0; m < 4; ++m) {
      __syncthreads();
#pragma unroll
      for (int n = 0; n < 4; ++n)
#pragma unroll
        for (int j = 0; j < 4; ++j) {
          float v = acc[m][n][j];
          if (by == 0) v = __expf(v);
          Lh[(wm * 16 + fq * 4 + j) * 136 + wn * 64 + n * 16 + fr] = (__bf16)v;
        }
      __syncthreads();
#pragma unroll
      for (int it = 0; it < 2; ++it) {
        int u = it * 512 + tid;
        int rr = u >> 4, cc = u & 15;
        int gch = (rr >> 4) * 64 + m * 16 + (rr & 15);
        bh8 val = *(const bh8*)&Lh[rr * 136 + cc * 8];
        *(bh8*)&dst[dbase + (size_t)gch * NPIX + cc * 8] = val;
      }
    }
  } else {
    const size_t obase = (size_t)b * CDIM * NPIX + (size_t)bx * 128;
    float* Ls = (float*)smem;       // [64][132] pad: 528B rows, 16B aligned
#pragma unroll
    for (int m = 0; m < 4; ++m) {
      __syncthreads();
#pragma unroll
      for (int n = 0; n < 4; ++n)
#pragma unroll
        for (int j = 0; j < 4; ++j)
          Ls[(wm * 16 + fq * 4 + j) * 132 + wn * 64 + n * 16 + fr] =
              acc[m][n][j] + bias[wm * 64 + m * 16 + fq * 4 + j];
      __syncthreads();
#pragma unroll
      for (int it = 0; it < 4; ++it) {
        int u = it * 512 + tid;
        int rr = u >> 5, cc = u & 31;
        int gch = (rr >> 4) * 64 + m * 16 + (rr & 15);
        fx4 val = *(const fx4*)&Ls[rr * 132 + cc * 4];
        *(fx4*)&fout[obase + (size_t)gch * NPIX + cc * 4] = val;
      }
    }
  }
}

// ---------------- pass 2: S[d][e] = sum_n ek[d,n] v[e,n]; Z[d]=sum_n ek ------
__global__ __launch_bounds__(256) void ctx_kernel(const __bf16* __restrict__ ekmat,
                                                  const __bf16* __restrict__ vmat,
                                                  float* __restrict__ S_part,
                                                  float* __restrict__ Zsum) {
  const int chunk = blockIdx.x, h = blockIdx.y, b = blockIdx.z;
  const int t = threadIdx.x;
  const int n0 = chunk * 256;
  __shared__ __bf16 EK[32 * 256];
  __shared__ __bf16 VS[32 * 256];
  __shared__ float zrow[32];

  if (t < 32) zrow[t] = 0.f;
#pragma unroll
  for (int i = 0; i < 4; ++i) {
    int e0 = i * 2048 + t * 8;
    int row = e0 >> 8, col = e0 & 255;
    gload16(ekmat + ((size_t)b * CDIM + h * 32 + row) * NPIX + n0 + col, (void*)(EK + e0));
    gload16(vmat  + ((size_t)b * CDIM + h * 32 + row) * NPIX + n0 + col, (void*)(VS + e0));
  }
  __syncthreads();

  {  // Z partial: thread t sums 32 values of row t>>3
    const int row = t >> 3, c0 = (t & 7) * 32;
    float zacc = 0.f;
#pragma unroll
    for (int i = 0; i < 4; ++i) {
      bh8 ev = *(const bh8*)&EK[row * 256 + c0 + i * 8];
#pragma unroll
      for (int j = 0; j < 8; ++j) zacc += (float)ev[j];
    }
    atomicAdd(&zrow[row], zacc);
  }

  const int wid = t >> 6, lane = t & 63, fr = lane & 15, fq = lane >> 4;
  fx4 acc[2][2] = {};
  const int kbase = wid * 64;
#pragma unroll
  for (int kk = 0; kk < 2; ++kk) {
    bh8 a[2], bb[2];
#pragma unroll
    for (int m = 0; m < 2; ++m)
      a[m] = *(const bh8*)&EK[(m * 16 + fr) * 256 + kbase + kk * 32 + fq * 8];
#pragma unroll
    for (int n = 0; n < 2; ++n)
      bb[n] = *(const bh8*)&VS[(n * 16 + fr) * 256 + kbase + kk * 32 + fq * 8];
#pragma unroll
    for (int m = 0; m < 2; ++m)
#pragma unroll
      for (int n = 0; n < 2; ++n) acc[m][n] = mfma16(a[m], bb[n], acc[m][n]);
  }
  __syncthreads();
  float* red = (float*)EK;
#pragma unroll
  for (int m = 0; m < 2; ++m)
#pragma unroll
    for (int n = 0; n < 2; ++n)
#pragma unroll
      for (int j = 0; j < 4; ++j)
        red[wid * 1024 + (m * 16 + fq * 4 + j) * 32 + (n * 16 + fr)] = acc[m][n][j];
  __syncthreads();
  const size_t bh = (size_t)b * 8 + h;
  for (int i = t; i < 1024; i += 256) {
    float s = red[i] + red[1024 + i] + red[2048 + i] + red[3072 + i];
    S_part[(bh * 64 + chunk) * 1024 + i] = s;
  }
  if (t < 32) atomicAdd(&Zsum[bh * 32 + t], zrow[t]);
}

// ---------------- pass 2.5: reduce S_part over chunks, divide by Z -> ctx ----
__global__ __launch_bounds__(256) void reduce_ctx(const float* __restrict__ S_part,
                                                  const float* __restrict__ Zsum,
                                                  float* __restrict__ ctx) {
  const int bh = blockIdx.x;
  const int t = threadIdx.x;
  for (int i = t; i < 1024; i += 256) {
    float s = 0.f;
    for (int ch = 0; ch < 64; ++ch) s += S_part[((size_t)bh * 64 + ch) * 1024 + i];
    ctx[(size_t)bh * 1024 + i] = s / Zsum[bh * 32 + (i >> 5)];
  }
}

// ---------------- pass 3: W2f[b][oc][h*32+d] = sum_e w_out[oc][h*32+e]*ctx ---
__global__ __launch_bounds__(256) void make_w2(const float* __restrict__ ctx,
                                               const float* __restrict__ w_out,
                                               float* __restrict__ W2f) {
  const int oc = blockIdx.x, b = blockIdx.y, t = threadIdx.x;
  const int h = t >> 5, d = t & 31;
  const float* wrow = w_out + oc * 256 + h * 32;
  const float* crow = ctx + (((size_t)b * 8 + h) * 32 + d) * 32;
  float s = 0.f;
#pragma unroll
  for (int e = 0; e < 32; ++e) s += wrow[e] * crow[e];
  W2f[((size_t)b * 256 + oc) * 256 + t] = s;
}

// ---------------- pass 3.5: W3[b] = W2f[b] (256x256) * Wq (256x256) -> bf16 --
// Wq = rows 0..255 of w_qkv (f32 row-major). out = W3 * x  ==  W2 * q.
__global__ __launch_bounds__(256) void make_w3(const float* __restrict__ W2f,
                                               const float* __restrict__ w_qkv,
                                               __bf16* __restrict__ W3) {
  const int ot = blockIdx.x, b = blockIdx.y, t = threadIdx.x;  // ot: 8 tiles x 32 oc
  __shared__ float w2s[32][256];
  const float* src = W2f + ((size_t)b * 256 + ot * 32) * 256;
  for (int i = t; i < 32 * 256; i += 256) w2s[i >> 8][i & 255] = src[i];
  __syncthreads();
  float acc[32] = {};
  for (int c = 0; c < 256; ++c) {
    float wq = w_qkv[c * 256 + t];  // Wq[c][t]
#pragma unroll
    for (int r = 0; r < 32; ++r) acc[r] += w2s[r][c] * wq;
  }
#pragma unroll
  for (int r = 0; r < 32; ++r)
    W3[((size_t)b * 256 + ot * 32 + r) * 256 + t] = (__bf16)acc[r];
}

extern "C" void kernel_launch(void* const* d_in, const int* in_sizes, int n_in,
                              void* d_out, int out_size, void* d_ws, size_t ws_size,
                              hipStream_t stream) {
  const float* x     = (const float*)d_in[0];
  const float* w_qkv = (const float*)d_in[1];
  const float* w_out = (const float*)d_in[2];
  const float* b_out = (const float*)d_in[3];
  float* out = (float*)d_out;

  char* ws = (char*)d_ws;
  __bf16* xT    = (__bf16*)(ws);                     // 67,108,864
  __bf16* wqb   = (__bf16*)(ws + 67108864ull);       // 393,216
  float*  W2f   = (float*) (ws + 67502080ull);       // 2,097,152
  __bf16* W3    = (__bf16*)(ws + 69599232ull);       // 1,048,576
  float*  S_part= (float*) (ws + 70647808ull);       // 16,777,216
  float*  Zsum  = (float*) (ws + 87425024ull);       // 8,192
  float*  ctx   = (float*) (ws + 87433216ull);       // 262,144 (end ~87.7 MB)

  // exp(k)/v bf16 scratch lives inside d_out (fully overwritten by final GEMM)
  __bf16* ekmat = (__bf16*)d_out;                      // [8][256][NPIX] 64 MiB
  __bf16* vmat  = ekmat + (size_t)BATCH * CDIM * NPIX; // next 64 MiB

  hipMemsetAsync(Zsum, 0, 8192, stream);

  conv_w<<<768, 256, 0, stream>>>(w_qkv, wqb, MQKV * CDIM);
  transpose_x<<<dim3(NPIX / 32, CDIM / 32, BATCH), 256, 0, stream>>>(x, xT);
  gemm256<0><<<dim3(NPIX / 128, 2, BATCH), 512, 0, stream>>>(
      wqb, xT, ekmat, vmat, nullptr, nullptr);
  ctx_kernel<<<dim3(64, 8, BATCH), 256, 0, stream>>>(ekmat, vmat, S_part, Zsum);
  reduce_ctx<<<64, 256, 0, stream>>>(S_part, Zsum, ctx);
  make_w2<<<dim3(256, BATCH), 256, 0, stream>>>(ctx, w_out, W2f);
  make_w3<<<dim3(8, BATCH), 256, 0, stream>>>(W2f, w_qkv, W3);
  gemm256<1><<<dim3(NPIX / 128, 1, BATCH), 512, 0, stream>>>(
      W3, xT, nullptr, nullptr, b_out, out);
}

// Round 6
// 247.896 us; speedup vs baseline: 1.0946x; 1.0946x over previous
//
#include <hip/hip_runtime.h>
#include <hip/hip_bf16.h>
#include <cstdint>

#define NPIX 16384   // h*w = 128*128
#define BATCH 8
#define CDIM 256
#define MQKV 768

typedef __bf16 bh8 __attribute__((ext_vector_type(8)));
typedef __bf16 bh4 __attribute__((ext_vector_type(4)));
typedef float  fx4 __attribute__((ext_vector_type(4)));

__device__ __forceinline__ void gload16(const void* g, void* l) {
  __builtin_amdgcn_global_load_lds(
      (const __attribute__((address_space(1))) uint32_t*)g,
      (__attribute__((address_space(3))) uint32_t*)l, 16, 0, 0);
}

__device__ __forceinline__ fx4 mfma16(bh8 a, bh8 b, fx4 c) {
  return __builtin_amdgcn_mfma_f32_16x16x32_bf16(a, b, c, 0, 0, 0);
}

__device__ __forceinline__ void pbar() {
  asm volatile("" ::: "memory");
  __builtin_amdgcn_s_barrier();
  asm volatile("" ::: "memory");
}
#define VMWI(n) asm volatile("s_waitcnt vmcnt(" #n ")" ::: "memory")

// ---------------- pass 0a: convert w_qkv f32 -> bf16 (row-major [768][256]) --
__global__ void conv_w(const float* __restrict__ w, __bf16* __restrict__ wb, int n) {
  int i = blockIdx.x * 256 + threadIdx.x;
  if (i < n) wb[i] = (__bf16)w[i];
}

// ---------------- pass 0a': WqT[t][o] = Wq[o][t] (first 256 rows), bf16 ------
__global__ __launch_bounds__(256) void transpose_wq(const float* __restrict__ w_qkv,
                                                    __bf16* __restrict__ wqT) {
  __shared__ float tile[32][33];
  const int t0 = blockIdx.x * 32, o0 = blockIdx.y * 32;
  const int tx = threadIdx.x & 31, ty = threadIdx.x >> 5;
#pragma unroll
  for (int j = 0; j < 4; ++j) {
    int r = ty * 4 + j;  // local o
    tile[r][tx] = w_qkv[(size_t)(o0 + r) * 256 + t0 + tx];
  }
  __syncthreads();
#pragma unroll
  for (int j = 0; j < 4; ++j) {
    int tl = ty * 4 + j; // local t
    wqT[(size_t)(t0 + tl) * 256 + o0 + tx] = (__bf16)tile[tx][tl];
  }
}

// ---------------- pass 0b: x [b][256][NPIX] f32 -> xT [b][NPIX][256] bf16 ----
__global__ __launch_bounds__(256) void transpose_x(const float* __restrict__ x,
                                                   __bf16* __restrict__ xT) {
  __shared__ float tile[32][33];
  const int n0 = blockIdx.x * 32, c0 = blockIdx.y * 32, b = blockIdx.z;
  const int tx = threadIdx.x & 31, ty = threadIdx.x >> 5;
#pragma unroll
  for (int j = 0; j < 4; ++j) {
    int r = ty * 4 + j;  // local c
    tile[r][tx] = x[((size_t)b * CDIM + c0 + r) * NPIX + n0 + tx];
  }
  __syncthreads();
#pragma unroll
  for (int j = 0; j < 4; ++j) {
    int nl = ty * 4 + j; // local n
    xT[((size_t)b * NPIX + n0 + nl) * CDIM + c0 + tx] = (__bf16)tile[tx][nl];
  }
}

// ====== 256x128 tile GEMM, K=256 as 8 half-tiles of 32 ======================
// A: per-wave register fragments loaded DIRECT from global (A is L2-resident
//    weight matrix shared by all blocks), alternating reg sets aX/aY,
//    prefetched one half-tile ahead.
// B: double-buffered LDS via global_load_lds, proven chunk-XOR swizzle
//    (16B chunk c of row r stored at c ^ (r&7); source pre-swizzled).
// vmcnt audit (per-thread outstanding sets at each wait) in comments.

#define BSP(pb) ((__bf16*)(smem + (pb)*16384))

#define STB(kt, pb)                                                            \
  do {                                                                         \
    _Pragma("unroll") for (int i_ = 0; i_ < 2; ++i_) {                         \
      int j_ = i_ * 512 + tid;                                                 \
      int row_ = j_ >> 3, c_ = j_ & 7;                                         \
      int sc_ = c_ ^ (row_ & 7);                                               \
      gload16(Bb + (size_t)row_ * 256 + (kt)*64 + sc_ * 8, BSP(pb) + j_ * 8);  \
    }                                                                          \
  } while (0)

#define LAH(dst, h)                                                            \
  do {                                                                         \
    _Pragma("unroll") for (int m_ = 0; m_ < 4; ++m_)                           \
      dst[m_] = *(const bh8*)(Ab + (size_t)(wm * 64 + m_ * 16 + fr) * 256 +    \
                              (h)*32 + fq * 8);                                \
  } while (0)

#define COMPH(ar, pb, hh)                                                      \
  do {                                                                         \
    bh8 b_[4];                                                                 \
    const int swk_ = ((hh)*4 + fq) ^ (fr & 7);                                 \
    _Pragma("unroll") for (int n_ = 0; n_ < 4; ++n_)                           \
      b_[n_] = *(const bh8*)&BSP(pb)[(wn * 64 + n_ * 16 + fr) * 64 + swk_ * 8];\
    __builtin_amdgcn_s_setprio(1);                                             \
    _Pragma("unroll") for (int m_ = 0; m_ < 4; ++m_)                           \
    _Pragma("unroll") for (int n_ = 0; n_ < 4; ++n_)                           \
      acc[m_][n_] = mfma16(ar[m_], b_[n_], acc[m_][n_]);                       \
    __builtin_amdgcn_s_setprio(0);                                             \
  } while (0)

// EPI==0: A = wqkv rows 256..767 (by=0 -> k with exp(), by=1 -> v)
// EPI==1: A = W3[b]; writes f32 out + bias
template <int EPI>
__global__ __launch_bounds__(512, 4) void gemm256(
    const __bf16* __restrict__ A, const __bf16* __restrict__ Bx,
    __bf16* __restrict__ ekmat, __bf16* __restrict__ vmat,
    const float* __restrict__ bias, float* __restrict__ fout) {
  __shared__ __align__(16) char smem[36864];
  const int tid = threadIdx.x;
  const int bx = blockIdx.x, by = blockIdx.y, b = blockIdx.z;
  const int lane = tid & 63, wid = tid >> 6;
  const int wm = wid >> 1, wn = wid & 1;
  const int fr = lane & 15, fq = lane >> 4;
  const __bf16* Ab = A + (size_t)((EPI == 0) ? (1 + by) : b) * 65536;
  const __bf16* Bb = Bx + ((size_t)b * NPIX + (size_t)bx * 128) * 256;

  fx4 acc[4][4] = {};
  bh8 aX[4], aY[4];

  // prologue: {LA0,STB0} must be older than {LA1,STB1} -> sched_barrier pin
  LAH(aX, 0); STB(0, 0);
  __builtin_amdgcn_sched_barrier(0);
  LAH(aY, 1); STB(1, 1);                 // out: LA0(4) STB0(2) | LA1(4) STB1(2)
  VMWI(6); pbar();                       // retire LA0+STB0; Bs[0] published
  COMPH(aX, 0, 0); LAH(aX, 2);           // out: LA1 STB1 LA2 = 10
  VMWI(6);                               // retire LA1
  COMPH(aY, 0, 1); pbar(); LAH(aY, 3); STB(2, 0);  // out: STB1 LA2 | LA3 STB2 = 12
  VMWI(6); pbar();                       // retire STB1+LA2; Bs[1] published
  COMPH(aX, 1, 0); LAH(aX, 4);           // out: LA3 STB2 LA4 = 10
  VMWI(6);                               // retire LA3
  COMPH(aY, 1, 1); pbar(); LAH(aY, 5); STB(3, 1);  // out: STB2 LA4 | LA5 STB3 = 12
  VMWI(6); pbar();                       // retire STB2+LA4; Bs[0] published
  COMPH(aX, 0, 0); LAH(aX, 6);           // out: LA5 STB3 LA6 = 10
  VMWI(6);                               // retire LA5
  COMPH(aY, 0, 1); pbar(); LAH(aY, 7);   // out: STB3 LA6 | LA7 = 10
  VMWI(4); pbar();                       // retire STB3+LA6; Bs[1] published
  COMPH(aX, 1, 0);
  VMWI(0);
  COMPH(aY, 1, 1);

  // ---- epilogue: per m-slice LDS bounce -> full-line coalesced writes
  if (EPI == 0) {
    __bf16* dst = (by == 0) ? ekmat : vmat;
    const size_t dbase = (size_t)b * CDIM * NPIX + (size_t)bx * 128;
    __bf16* Lh = (__bf16*)smem;     // [64][136] pad: 272B rows, 16B aligned
#pragma unroll
    for (int m = 0; m < 4; ++m) {
      __syncthreads();
#pragma unroll
      for (int n = 0; n < 4; ++n)
#pragma unroll
        for (int j = 0; j < 4; ++j) {
          float v = acc[m][n][j];
          if (by == 0) v = __expf(v);
          Lh[(wm * 16 + fq * 4 + j) * 136 + wn * 64 + n * 16 + fr] = (__bf16)v;
        }
      __syncthreads();
#pragma unroll
      for (int it = 0; it < 2; ++it) {
        int u = it * 512 + tid;
        int rr = u >> 4, cc = u & 15;
        int gch = (rr >> 4) * 64 + m * 16 + (rr & 15);
        bh8 val = *(const bh8*)&Lh[rr * 136 + cc * 8];
        *(bh8*)&dst[dbase + (size_t)gch * NPIX + cc * 8] = val;
      }
    }
  } else {
    const size_t obase = (size_t)b * CDIM * NPIX + (size_t)bx * 128;
    float* Ls = (float*)smem;       // [64][132] pad: 528B rows, 16B aligned
#pragma unroll
    for (int m = 0; m < 4; ++m) {
      __syncthreads();
#pragma unroll
      for (int n = 0; n < 4; ++n)
#pragma unroll
        for (int j = 0; j < 4; ++j)
          Ls[(wm * 16 + fq * 4 + j) * 132 + wn * 64 + n * 16 + fr] =
              acc[m][n][j] + bias[wm * 64 + m * 16 + fq * 4 + j];
      __syncthreads();
#pragma unroll
      for (int it = 0; it < 4; ++it) {
        int u = it * 512 + tid;
        int rr = u >> 5, cc = u & 31;
        int gch = (rr >> 4) * 64 + m * 16 + (rr & 15);
        fx4 val = *(const fx4*)&Ls[rr * 132 + cc * 4];
        *(fx4*)&fout[obase + (size_t)gch * NPIX + cc * 4] = val;
      }
    }
  }
}

// ---------------- pass 2: S[d][e] = sum_n ek[d,n] v[e,n]; Z[d]=sum_n ek ------
__global__ __launch_bounds__(256) void ctx_kernel(const __bf16* __restrict__ ekmat,
                                                  const __bf16* __restrict__ vmat,
                                                  float* __restrict__ S_part,
                                                  float* __restrict__ Zsum) {
  const int chunk = blockIdx.x, h = blockIdx.y, b = blockIdx.z;
  const int t = threadIdx.x;
  const int n0 = chunk * 256;
  __shared__ __bf16 EK[32 * 256];
  __shared__ __bf16 VS[32 * 256];
  __shared__ float zrow[32];

  if (t < 32) zrow[t] = 0.f;
#pragma unroll
  for (int i = 0; i < 4; ++i) {
    int e0 = i * 2048 + t * 8;
    int row = e0 >> 8, col = e0 & 255;
    gload16(ekmat + ((size_t)b * CDIM + h * 32 + row) * NPIX + n0 + col, (void*)(EK + e0));
    gload16(vmat  + ((size_t)b * CDIM + h * 32 + row) * NPIX + n0 + col, (void*)(VS + e0));
  }
  __syncthreads();

  {  // Z partial: thread t sums 32 values of row t>>3
    const int row = t >> 3, c0 = (t & 7) * 32;
    float zacc = 0.f;
#pragma unroll
    for (int i = 0; i < 4; ++i) {
      bh8 ev = *(const bh8*)&EK[row * 256 + c0 + i * 8];
#pragma unroll
      for (int j = 0; j < 8; ++j) zacc += (float)ev[j];
    }
    atomicAdd(&zrow[row], zacc);
  }

  const int wid = t >> 6, lane = t & 63, fr = lane & 15, fq = lane >> 4;
  fx4 acc[2][2] = {};
  const int kbase = wid * 64;
#pragma unroll
  for (int kk = 0; kk < 2; ++kk) {
    bh8 a[2], bb[2];
#pragma unroll
    for (int m = 0; m < 2; ++m)
      a[m] = *(const bh8*)&EK[(m * 16 + fr) * 256 + kbase + kk * 32 + fq * 8];
#pragma unroll
    for (int n = 0; n < 2; ++n)
      bb[n] = *(const bh8*)&VS[(n * 16 + fr) * 256 + kbase + kk * 32 + fq * 8];
#pragma unroll
    for (int m = 0; m < 2; ++m)
#pragma unroll
      for (int n = 0; n < 2; ++n) acc[m][n] = mfma16(a[m], bb[n], acc[m][n]);
  }
  __syncthreads();
  float* red = (float*)EK;
#pragma unroll
  for (int m = 0; m < 2; ++m)
#pragma unroll
    for (int n = 0; n < 2; ++n)
#pragma unroll
      for (int j = 0; j < 4; ++j)
        red[wid * 1024 + (m * 16 + fq * 4 + j) * 32 + (n * 16 + fr)] = acc[m][n][j];
  __syncthreads();
  const size_t bh = (size_t)b * 8 + h;
  for (int i = t; i < 1024; i += 256) {
    float s = red[i] + red[1024 + i] + red[2048 + i] + red[3072 + i];
    S_part[(bh * 64 + chunk) * 1024 + i] = s;
  }
  if (t < 32) atomicAdd(&Zsum[bh * 32 + t], zrow[t]);
}

// ---------------- pass 2.5: reduce S_part over chunks, divide by Z -> ctx ----
__global__ __launch_bounds__(256) void reduce_ctx(const float* __restrict__ S_part,
                                                  const float* __restrict__ Zsum,
                                                  float* __restrict__ ctx) {
  const int bh = blockIdx.x;
  const int t = threadIdx.x;
  for (int i = t; i < 1024; i += 256) {
    float s = 0.f;
    for (int ch = 0; ch < 64; ++ch) s += S_part[((size_t)bh * 64 + ch) * 1024 + i];
    ctx[(size_t)bh * 1024 + i] = s / Zsum[bh * 32 + (i >> 5)];
  }
}

// ---------------- pass 3: W2b[b][oc][h*32+d] = sum_e w_out[oc][h*32+e]*ctx ---
__global__ __launch_bounds__(256) void make_w2(const float* __restrict__ ctx,
                                               const float* __restrict__ w_out,
                                               __bf16* __restrict__ W2b) {
  const int oc = blockIdx.x, b = blockIdx.y, t = threadIdx.x;
  const int h = t >> 5, d = t & 31;
  const float* wrow = w_out + oc * 256 + h * 32;
  const float* crow = ctx + (((size_t)b * 8 + h) * 32 + d) * 32;
  float s = 0.f;
#pragma unroll
  for (int e = 0; e < 32; ++e) s += wrow[e] * crow[e];
  W2b[((size_t)b * 256 + oc) * 256 + t] = (__bf16)s;
}

// ---------------- pass 3.5: W3[b] = W2b[b] (256x256) x Wq (256x256), MFMA ----
// W3[r][t] = sum_o W2b[r][o] * WqT[t][o].  Grid (2,2,8), 256 thr (4 waves).
__global__ __launch_bounds__(256) void make_w3(const __bf16* __restrict__ W2b,
                                               const __bf16* __restrict__ wqT,
                                               __bf16* __restrict__ W3) {
  const int bx = blockIdx.x, by = blockIdx.y, b = blockIdx.z;
  const int lane = threadIdx.x & 63, wid = threadIdx.x >> 6;
  const int wm = wid >> 1, wn = wid & 1;
  const int fr = lane & 15, fq = lane >> 4;
  const __bf16* Ab = W2b + (size_t)b * 65536 + (size_t)(by * 128 + wm * 64) * 256;
  const __bf16* Bb = wqT + (size_t)(bx * 128 + wn * 64) * 256;
  fx4 acc[4][4] = {};
#pragma unroll
  for (int h = 0; h < 8; ++h) {
    bh8 a_[4], b_[4];
#pragma unroll
    for (int m = 0; m < 4; ++m)
      a_[m] = *(const bh8*)(Ab + (size_t)(m * 16 + fr) * 256 + h * 32 + fq * 8);
#pragma unroll
    for (int n = 0; n < 4; ++n)
      b_[n] = *(const bh8*)(Bb + (size_t)(n * 16 + fr) * 256 + h * 32 + fq * 8);
#pragma unroll
    for (int m = 0; m < 4; ++m)
#pragma unroll
      for (int n = 0; n < 4; ++n) acc[m][n] = mfma16(a_[m], b_[n], acc[m][n]);
  }
#pragma unroll
  for (int m = 0; m < 4; ++m)
#pragma unroll
    for (int n = 0; n < 4; ++n) {
      int r0 = by * 128 + wm * 64 + m * 16 + fq * 4;
      int t0 = bx * 128 + wn * 64 + n * 16 + fr;
      bh4 v4;
#pragma unroll
      for (int j = 0; j < 4; ++j) v4[j] = (__bf16)acc[m][n][j];
#pragma unroll
      for (int j = 0; j < 4; ++j)
        W3[(size_t)b * 65536 + (size_t)(r0 + j) * 256 + t0] = v4[j];
    }
}

extern "C" void kernel_launch(void* const* d_in, const int* in_sizes, int n_in,
                              void* d_out, int out_size, void* d_ws, size_t ws_size,
                              hipStream_t stream) {
  const float* x     = (const float*)d_in[0];
  const float* w_qkv = (const float*)d_in[1];
  const float* w_out = (const float*)d_in[2];
  const float* b_out = (const float*)d_in[3];
  float* out = (float*)d_out;

  char* ws = (char*)d_ws;
  __bf16* xT    = (__bf16*)(ws);                     // 67,108,864
  __bf16* wqb   = (__bf16*)(ws + 67108864ull);       // 393,216
  __bf16* wqT   = (__bf16*)(ws + 67502080ull);       // 131,072
  __bf16* W2b   = (__bf16*)(ws + 67633152ull);       // 1,048,576
  __bf16* W3    = (__bf16*)(ws + 68681728ull);       // 1,048,576
  float*  S_part= (float*) (ws + 69730304ull);       // 16,777,216
  float*  Zsum  = (float*) (ws + 86507520ull);       // 8,192
  float*  ctx   = (float*) (ws + 86515712ull);       // 262,144 (end ~86.8 MB)

  // exp(k)/v bf16 scratch lives inside d_out (fully overwritten by final GEMM)
  __bf16* ekmat = (__bf16*)d_out;                      // [8][256][NPIX] 64 MiB
  __bf16* vmat  = ekmat + (size_t)BATCH * CDIM * NPIX; // next 64 MiB

  hipMemsetAsync(Zsum, 0, 8192, stream);

  conv_w<<<768, 256, 0, stream>>>(w_qkv, wqb, MQKV * CDIM);
  transpose_wq<<<dim3(8, 8), 256, 0, stream>>>(w_qkv, wqT);
  transpose_x<<<dim3(NPIX / 32, CDIM / 32, BATCH), 256, 0, stream>>>(x, xT);
  gemm256<0><<<dim3(NPIX / 128, 2, BATCH), 512, 0, stream>>>(
      wqb, xT, ekmat, vmat, nullptr, nullptr);
  ctx_kernel<<<dim3(64, 8, BATCH), 256, 0, stream>>>(ekmat, vmat, S_part, Zsum);
  reduce_ctx<<<64, 256, 0, stream>>>(S_part, Zsum, ctx);
  make_w2<<<dim3(256, BATCH), 256, 0, stream>>>(ctx, w_out, W2b);
  make_w3<<<dim3(2, 2, BATCH), 256, 0, stream>>>(W2b, wqT, W3);
  gemm256<1><<<dim3(NPIX / 128, 1, BATCH), 512, 0, stream>>>(
      W3, xT, nullptr, nullptr, b_out, out);
}

// Round 7
// 201.299 us; speedup vs baseline: 1.3480x; 1.2315x over previous
//
#include <hip/hip_runtime.h>
#include <hip/hip_bf16.h>
#include <cstdint>

#define NPIX 16384   // h*w = 128*128
#define BATCH 8
#define CDIM 256
#define MQKV 768

typedef __bf16 bh8 __attribute__((ext_vector_type(8)));
typedef __bf16 bh4 __attribute__((ext_vector_type(4)));
typedef float  fx4 __attribute__((ext_vector_type(4)));

__device__ __forceinline__ void gload16(const void* g, void* l) {
  __builtin_amdgcn_global_load_lds(
      (const __attribute__((address_space(1))) uint32_t*)g,
      (__attribute__((address_space(3))) uint32_t*)l, 16, 0, 0);
}

__device__ __forceinline__ fx4 mfma16(bh8 a, bh8 b, fx4 c) {
  return __builtin_amdgcn_mfma_f32_16x16x32_bf16(a, b, c, 0, 0, 0);
}

__device__ __forceinline__ void pbar() {
  asm volatile("" ::: "memory");
  __builtin_amdgcn_s_barrier();
  asm volatile("" ::: "memory");
}
#define VMWI(n) asm volatile("s_waitcnt vmcnt(" #n ")" ::: "memory")

// ---------------- pass 0a: convert w_qkv f32 -> bf16 (row-major [768][256]) --
__global__ void conv_w(const float* __restrict__ w, __bf16* __restrict__ wb, int n) {
  int i = blockIdx.x * 256 + threadIdx.x;
  if (i < n) wb[i] = (__bf16)w[i];
}

// ---------------- pass 0a': WqT[t][o] = Wq[o][t] (first 256 rows), bf16 ------
__global__ __launch_bounds__(256) void transpose_wq(const float* __restrict__ w_qkv,
                                                    __bf16* __restrict__ wqT) {
  __shared__ float tile[32][33];
  const int t0 = blockIdx.x * 32, o0 = blockIdx.y * 32;
  const int tx = threadIdx.x & 31, ty = threadIdx.x >> 5;
#pragma unroll
  for (int j = 0; j < 4; ++j) {
    int r = ty * 4 + j;  // local o
    tile[r][tx] = w_qkv[(size_t)(o0 + r) * 256 + t0 + tx];
  }
  __syncthreads();
#pragma unroll
  for (int j = 0; j < 4; ++j) {
    int tl = ty * 4 + j; // local t
    wqT[(size_t)(t0 + tl) * 256 + o0 + tx] = (__bf16)tile[tx][tl];
  }
}

// ---------------- pass 0b: x [b][256][NPIX] f32 -> xT [b][NPIX][256] bf16 ----
// 64c x 32n tiles; 16B/lane coalesced bf16 writes.
__global__ __launch_bounds__(256) void transpose_x(const float* __restrict__ x,
                                                   __bf16* __restrict__ xT) {
  __shared__ float tf[64][33];
  const int n0 = blockIdx.x * 32, c0 = blockIdx.y * 64, b = blockIdx.z;
  const int u = threadIdx.x;
  const int tx = u & 31, tg = u >> 5;  // tg 0..7
#pragma unroll
  for (int j = 0; j < 8; ++j) {
    int r = tg * 8 + j;  // local c 0..63
    tf[r][tx] = x[((size_t)b * CDIM + c0 + r) * NPIX + n0 + tx];
  }
  __syncthreads();
  const int nl = u >> 3, cl = (u & 7) * 8;
  bh8 v;
#pragma unroll
  for (int j = 0; j < 8; ++j) v[j] = (__bf16)tf[cl + j][nl];
  *(bh8*)&xT[((size_t)b * NPIX + n0 + nl) * CDIM + c0 + cl] = v;
}

// ====== 256x128 tile GEMM, K=256 as 4 x BK=64 (r5-proven schedule) ==========
// A single-buffered (32KB), B double-buffered (2x16KB). Staging via
// global_load_lds, conflict-free chunk-XOR swizzle (16B chunk c of row r
// stored at c ^ (r&7); source pre-swizzled). Counted vmcnt(2) per step.
// vmcnt audit (per-thread, in-order): STB=2 loads, STA=4.
//   STB0 STA0 STB1 -> 8 out; VMWI(2) retires STB0+STA0 -> COMP(0) safe.
//   loop invariant: before each COMP, VMWI(2) leaves only next-B in flight.
// Epilogue: per m-slice LDS bounce -> full-cacheline coalesced writes.

#define BSP(pb) ((__bf16*)(smem + 32768 + (pb)*16384))

#define STA(kt)                                                                \
  do {                                                                         \
    _Pragma("unroll") for (int i_ = 0; i_ < 4; ++i_) {                         \
      int j_ = i_ * 512 + tid;                                                 \
      int row_ = j_ >> 3, c_ = j_ & 7;                                         \
      int sc_ = c_ ^ (row_ & 7);                                               \
      gload16(Ab + (size_t)row_ * 256 + (kt)*64 + sc_ * 8, As + j_ * 8);       \
    }                                                                          \
  } while (0)

#define STB(kt, pb)                                                            \
  do {                                                                         \
    _Pragma("unroll") for (int i_ = 0; i_ < 2; ++i_) {                         \
      int j_ = i_ * 512 + tid;                                                 \
      int row_ = j_ >> 3, c_ = j_ & 7;                                         \
      int sc_ = c_ ^ (row_ & 7);                                               \
      gload16(Bb + (size_t)row_ * 256 + (kt)*64 + sc_ * 8, BSP(pb) + j_ * 8);  \
    }                                                                          \
  } while (0)

#define COMP(pb)                                                               \
  do {                                                                         \
    _Pragma("unroll") for (int ks_ = 0; ks_ < 2; ++ks_) {                      \
      bh8 a_[4], b_[4];                                                        \
      const int swk_ = (ks_ * 4 + fq) ^ (fr & 7);                              \
      _Pragma("unroll") for (int m_ = 0; m_ < 4; ++m_)                         \
        a_[m_] = *(const bh8*)&As[(wm * 64 + m_ * 16 + fr) * 64 + swk_ * 8];   \
      _Pragma("unroll") for (int n_ = 0; n_ < 4; ++n_)                         \
        b_[n_] = *(const bh8*)&BSP(pb)[(wn * 64 + n_ * 16 + fr) * 64 + swk_ * 8];\
      _Pragma("unroll") for (int m_ = 0; m_ < 4; ++m_)                         \
      _Pragma("unroll") for (int n_ = 0; n_ < 4; ++n_)                         \
        acc[m_][n_] = mfma16(a_[m_], b_[n_], acc[m_][n_]);                     \
    }                                                                          \
  } while (0)

// EPI==0: A = wqkv rows 256..767 (by=0 -> k with exp(), by=1 -> v)
// EPI==1: A = W3[b]; writes f32 out + bias
template <int EPI>
__global__ __launch_bounds__(512, 4) void gemm256(
    const __bf16* __restrict__ A, const __bf16* __restrict__ Bx,
    __bf16* __restrict__ ekmat, __bf16* __restrict__ vmat,
    const float* __restrict__ bias, float* __restrict__ fout) {
  __shared__ __align__(16) char smem[65536];
  __bf16* As = (__bf16*)smem;       // [256 rows][64 k] 32KB
  const int tid = threadIdx.x;
  const int bx = blockIdx.x, by = blockIdx.y, b = blockIdx.z;
  const int lane = tid & 63, wid = tid >> 6;
  const int wm = wid >> 1, wn = wid & 1;
  const int fr = lane & 15, fq = lane >> 4;
  const __bf16* Ab = A + (size_t)((EPI == 0) ? (1 + by) : b) * 65536;
  const __bf16* Bb = Bx + ((size_t)b * NPIX + (size_t)bx * 128) * 256;

  fx4 acc[4][4] = {};

  STB(0, 0); STA(0);
  STB(1, 1); VMWI(2); pbar(); COMP(0); pbar(); STA(1);
  STB(2, 0); VMWI(2); pbar(); COMP(1); pbar(); STA(2);
  STB(3, 1); VMWI(2); pbar(); COMP(0); pbar(); STA(3);
             VMWI(0); pbar(); COMP(1); pbar();

  // ---- epilogue: per m-slice LDS bounce -> full-line coalesced writes
  if (EPI == 0) {
    __bf16* dst = (by == 0) ? ekmat : vmat;
    const size_t dbase = (size_t)b * CDIM * NPIX + (size_t)bx * 128;
    __bf16* Lh = (__bf16*)smem;     // [64][136] pad: 272B rows, 16B aligned
#pragma unroll
    for (int m = 0; m < 4; ++m) {
      __syncthreads();
#pragma unroll
      for (int n = 0; n < 4; ++n)
#pragma unroll
        for (int j = 0; j < 4; ++j) {
          float v = acc[m][n][j];
          if (by == 0) v = __expf(v);
          Lh[(wm * 16 + fq * 4 + j) * 136 + wn * 64 + n * 16 + fr] = (__bf16)v;
        }
      __syncthreads();
#pragma unroll
      for (int it = 0; it < 2; ++it) {
        int u = it * 512 + tid;
        int rr = u >> 4, cc = u & 15;
        int gch = (rr >> 4) * 64 + m * 16 + (rr & 15);
        bh8 val = *(const bh8*)&Lh[rr * 136 + cc * 8];
        *(bh8*)&dst[dbase + (size_t)gch * NPIX + cc * 8] = val;
      }
    }
  } else {
    const size_t obase = (size_t)b * CDIM * NPIX + (size_t)bx * 128;
    float* Ls = (float*)smem;       // [64][132] pad: 528B rows, 16B aligned
#pragma unroll
    for (int m = 0; m < 4; ++m) {
      __syncthreads();
#pragma unroll
      for (int n = 0; n < 4; ++n)
#pragma unroll
        for (int j = 0; j < 4; ++j)
          Ls[(wm * 16 + fq * 4 + j) * 132 + wn * 64 + n * 16 + fr] =
              acc[m][n][j] + bias[wm * 64 + m * 16 + fq * 4 + j];
      __syncthreads();
#pragma unroll
      for (int it = 0; it < 4; ++it) {
        int u = it * 512 + tid;
        int rr = u >> 5, cc = u & 31;
        int gch = (rr >> 4) * 64 + m * 16 + (rr & 15);
        fx4 val = *(const fx4*)&Ls[rr * 132 + cc * 4];
        *(fx4*)&fout[obase + (size_t)gch * NPIX + cc * 4] = val;
      }
    }
  }
}

// ---------------- pass 2: S[d][e] = sum_n ek[d,n] v[e,n]; Z[d]=sum_n ek ------
__global__ __launch_bounds__(256) void ctx_kernel(const __bf16* __restrict__ ekmat,
                                                  const __bf16* __restrict__ vmat,
                                                  float* __restrict__ S_part,
                                                  float* __restrict__ Zsum) {
  const int chunk = blockIdx.x, h = blockIdx.y, b = blockIdx.z;
  const int t = threadIdx.x;
  const int n0 = chunk * 256;
  __shared__ __bf16 EK[32 * 256];
  __shared__ __bf16 VS[32 * 256];
  __shared__ float zrow[32];

  if (t < 32) zrow[t] = 0.f;
#pragma unroll
  for (int i = 0; i < 4; ++i) {
    int e0 = i * 2048 + t * 8;
    int row = e0 >> 8, col = e0 & 255;
    gload16(ekmat + ((size_t)b * CDIM + h * 32 + row) * NPIX + n0 + col, (void*)(EK + e0));
    gload16(vmat  + ((size_t)b * CDIM + h * 32 + row) * NPIX + n0 + col, (void*)(VS + e0));
  }
  __syncthreads();

  {  // Z partial: thread t sums 32 values of row t>>3
    const int row = t >> 3, c0 = (t & 7) * 32;
    float zacc = 0.f;
#pragma unroll
    for (int i = 0; i < 4; ++i) {
      bh8 ev = *(const bh8*)&EK[row * 256 + c0 + i * 8];
#pragma unroll
      for (int j = 0; j < 8; ++j) zacc += (float)ev[j];
    }
    atomicAdd(&zrow[row], zacc);
  }

  const int wid = t >> 6, lane = t & 63, fr = lane & 15, fq = lane >> 4;
  fx4 acc[2][2] = {};
  const int kbase = wid * 64;
#pragma unroll
  for (int kk = 0; kk < 2; ++kk) {
    bh8 a[2], bb[2];
#pragma unroll
    for (int m = 0; m < 2; ++m)
      a[m] = *(const bh8*)&EK[(m * 16 + fr) * 256 + kbase + kk * 32 + fq * 8];
#pragma unroll
    for (int n = 0; n < 2; ++n)
      bb[n] = *(const bh8*)&VS[(n * 16 + fr) * 256 + kbase + kk * 32 + fq * 8];
#pragma unroll
    for (int m = 0; m < 2; ++m)
#pragma unroll
      for (int n = 0; n < 2; ++n) acc[m][n] = mfma16(a[m], bb[n], acc[m][n]);
  }
  __syncthreads();
  float* red = (float*)EK;
#pragma unroll
  for (int m = 0; m < 2; ++m)
#pragma unroll
    for (int n = 0; n < 2; ++n)
#pragma unroll
      for (int j = 0; j < 4; ++j)
        red[wid * 1024 + (m * 16 + fq * 4 + j) * 32 + (n * 16 + fr)] = acc[m][n][j];
  __syncthreads();
  const size_t bh = (size_t)b * 8 + h;
  for (int i = t; i < 1024; i += 256) {
    float s = red[i] + red[1024 + i] + red[2048 + i] + red[3072 + i];
    S_part[(bh * 64 + chunk) * 1024 + i] = s;
  }
  if (t < 32) atomicAdd(&Zsum[bh * 32 + t], zrow[t]);
}

// ---------------- pass 2.5: reduce S_part over chunks, divide by Z -> ctx ----
__global__ __launch_bounds__(256) void reduce_ctx(const float* __restrict__ S_part,
                                                  const float* __restrict__ Zsum,
                                                  float* __restrict__ ctx) {
  const int bh = blockIdx.x;
  const int t = threadIdx.x;
  for (int i = t; i < 1024; i += 256) {
    float s = 0.f;
    for (int ch = 0; ch < 64; ++ch) s += S_part[((size_t)bh * 64 + ch) * 1024 + i];
    ctx[(size_t)bh * 1024 + i] = s / Zsum[bh * 32 + (i >> 5)];
  }
}

// ---------------- pass 3: W2b[b][oc][h*32+d] = sum_e w_out[oc][h*32+e]*ctx ---
__global__ __launch_bounds__(256) void make_w2(const float* __restrict__ ctx,
                                               const float* __restrict__ w_out,
                                               __bf16* __restrict__ W2b) {
  const int oc = blockIdx.x, b = blockIdx.y, t = threadIdx.x;
  const int h = t >> 5, d = t & 31;
  const float* wrow = w_out + oc * 256 + h * 32;
  const float* crow = ctx + (((size_t)b * 8 + h) * 32 + d) * 32;
  float s = 0.f;
#pragma unroll
  for (int e = 0; e < 32; ++e) s += wrow[e] * crow[e];
  W2b[((size_t)b * 256 + oc) * 256 + t] = (__bf16)s;
}

// ---------------- pass 3.5: W3[b] = W2b[b] (256x256) x Wq (256x256), MFMA ----
// W3[r][t] = sum_o W2b[r][o] * WqT[t][o].  Grid (2,2,8), 256 thr (4 waves).
__global__ __launch_bounds__(256) void make_w3(const __bf16* __restrict__ W2b,
                                               const __bf16* __restrict__ wqT,
                                               __bf16* __restrict__ W3) {
  const int bx = blockIdx.x, by = blockIdx.y, b = blockIdx.z;
  const int lane = threadIdx.x & 63, wid = threadIdx.x >> 6;
  const int wm = wid >> 1, wn = wid & 1;
  const int fr = lane & 15, fq = lane >> 4;
  const __bf16* Ab = W2b + (size_t)b * 65536 + (size_t)(by * 128 + wm * 64) * 256;
  const __bf16* Bb = wqT + (size_t)(bx * 128 + wn * 64) * 256;
  fx4 acc[4][4] = {};
#pragma unroll
  for (int h = 0; h < 8; ++h) {
    bh8 a_[4], b_[4];
#pragma unroll
    for (int m = 0; m < 4; ++m)
      a_[m] = *(const bh8*)(Ab + (size_t)(m * 16 + fr) * 256 + h * 32 + fq * 8);
#pragma unroll
    for (int n = 0; n < 4; ++n)
      b_[n] = *(const bh8*)(Bb + (size_t)(n * 16 + fr) * 256 + h * 32 + fq * 8);
#pragma unroll
    for (int m = 0; m < 4; ++m)
#pragma unroll
      for (int n = 0; n < 4; ++n) acc[m][n] = mfma16(a_[m], b_[n], acc[m][n]);
  }
#pragma unroll
  for (int m = 0; m < 4; ++m)
#pragma unroll
    for (int n = 0; n < 4; ++n) {
      int r0 = by * 128 + wm * 64 + m * 16 + fq * 4;
      int t0 = bx * 128 + wn * 64 + n * 16 + fr;
#pragma unroll
      for (int j = 0; j < 4; ++j)
        W3[(size_t)b * 65536 + (size_t)(r0 + j) * 256 + t0] = (__bf16)acc[m][n][j];
    }
}

extern "C" void kernel_launch(void* const* d_in, const int* in_sizes, int n_in,
                              void* d_out, int out_size, void* d_ws, size_t ws_size,
                              hipStream_t stream) {
  const float* x     = (const float*)d_in[0];
  const float* w_qkv = (const float*)d_in[1];
  const float* w_out = (const float*)d_in[2];
  const float* b_out = (const float*)d_in[3];
  float* out = (float*)d_out;

  char* ws = (char*)d_ws;
  __bf16* xT    = (__bf16*)(ws);                     // 67,108,864
  __bf16* wqb   = (__bf16*)(ws + 67108864ull);       // 393,216
  __bf16* wqT   = (__bf16*)(ws + 67502080ull);       // 131,072
  __bf16* W2b   = (__bf16*)(ws + 67633152ull);       // 1,048,576
  __bf16* W3    = (__bf16*)(ws + 68681728ull);       // 1,048,576
  float*  S_part= (float*) (ws + 69730304ull);       // 16,777,216
  float*  Zsum  = (float*) (ws + 86507520ull);       // 8,192
  float*  ctx   = (float*) (ws + 86515712ull);       // 262,144 (end ~86.8 MB)

  // exp(k)/v bf16 scratch lives inside d_out (fully overwritten by final GEMM)
  __bf16* ekmat = (__bf16*)d_out;                      // [8][256][NPIX] 64 MiB
  __bf16* vmat  = ekmat + (size_t)BATCH * CDIM * NPIX; // next 64 MiB

  hipMemsetAsync(Zsum, 0, 8192, stream);

  conv_w<<<768, 256, 0, stream>>>(w_qkv, wqb, MQKV * CDIM);
  transpose_wq<<<dim3(8, 8), 256, 0, stream>>>(w_qkv, wqT);
  transpose_x<<<dim3(NPIX / 32, CDIM / 64, BATCH), 256, 0, stream>>>(x, xT);
  gemm256<0><<<dim3(NPIX / 128, 2, BATCH), 512, 0, stream>>>(
      wqb, xT, ekmat, vmat, nullptr, nullptr);
  ctx_kernel<<<dim3(64, 8, BATCH), 256, 0, stream>>>(ekmat, vmat, S_part, Zsum);
  reduce_ctx<<<64, 256, 0, stream>>>(S_part, Zsum, ctx);
  make_w2<<<dim3(256, BATCH), 256, 0, stream>>>(ctx, w_out, W2b);
  make_w3<<<dim3(2, 2, BATCH), 256, 0, stream>>>(W2b, wqT, W3);
  gemm256<1><<<dim3(NPIX / 128, 1, BATCH), 512, 0, stream>>>(
      W3, xT, nullptr, nullptr, b_out, out);
}

// Round 8
// 199.546 us; speedup vs baseline: 1.3599x; 1.0088x over previous
//
#include <hip/hip_runtime.h>
#include <hip/hip_bf16.h>
#include <cstdint>

#define NPIX 16384   // h*w = 128*128
#define BATCH 8
#define CDIM 256
#define MQKV 768

typedef __bf16 bh8 __attribute__((ext_vector_type(8)));
typedef __bf16 bh4 __attribute__((ext_vector_type(4)));
typedef float  fx4 __attribute__((ext_vector_type(4)));

__device__ __forceinline__ void gload16(const void* g, void* l) {
  __builtin_amdgcn_global_load_lds(
      (const __attribute__((address_space(1))) uint32_t*)g,
      (__attribute__((address_space(3))) uint32_t*)l, 16, 0, 0);
}

__device__ __forceinline__ fx4 mfma16(bh8 a, bh8 b, fx4 c) {
  return __builtin_amdgcn_mfma_f32_16x16x32_bf16(a, b, c, 0, 0, 0);
}

__device__ __forceinline__ void pbar() {
  asm volatile("" ::: "memory");
  __builtin_amdgcn_s_barrier();
  asm volatile("" ::: "memory");
}
#define VMWI(n) asm volatile("s_waitcnt vmcnt(" #n ")" ::: "memory")

// ---------------- pass 0a: convert w_qkv f32 -> bf16 (row-major [768][256]) --
__global__ void conv_w(const float* __restrict__ w, __bf16* __restrict__ wb, int n) {
  int i = blockIdx.x * 256 + threadIdx.x;
  if (i < n) wb[i] = (__bf16)w[i];
}

// ---------------- pass 0a': WqT[t][o] = Wq[o][t] (first 256 rows), bf16 ------
__global__ __launch_bounds__(256) void transpose_wq(const float* __restrict__ w_qkv,
                                                    __bf16* __restrict__ wqT) {
  __shared__ float tile[32][33];
  const int t0 = blockIdx.x * 32, o0 = blockIdx.y * 32;
  const int tx = threadIdx.x & 31, ty = threadIdx.x >> 5;
#pragma unroll
  for (int j = 0; j < 4; ++j) {
    int r = ty * 4 + j;  // local o
    tile[r][tx] = w_qkv[(size_t)(o0 + r) * 256 + t0 + tx];
  }
  __syncthreads();
#pragma unroll
  for (int j = 0; j < 4; ++j) {
    int tl = ty * 4 + j; // local t
    wqT[(size_t)(t0 + tl) * 256 + o0 + tx] = (__bf16)tile[tx][tl];
  }
}

// ---------------- pass 0b: x [b][256][NPIX] f32 -> xT [b][NPIX][256] bf16 ----
// 64c x 32n tiles; 16B/lane coalesced bf16 writes.
__global__ __launch_bounds__(256) void transpose_x(const float* __restrict__ x,
                                                   __bf16* __restrict__ xT) {
  __shared__ float tf[64][33];
  const int n0 = blockIdx.x * 32, c0 = blockIdx.y * 64, b = blockIdx.z;
  const int u = threadIdx.x;
  const int tx = u & 31, tg = u >> 5;  // tg 0..7
#pragma unroll
  for (int j = 0; j < 8; ++j) {
    int r = tg * 8 + j;  // local c 0..63
    tf[r][tx] = x[((size_t)b * CDIM + c0 + r) * NPIX + n0 + tx];
  }
  __syncthreads();
  const int nl = u >> 3, cl = (u & 7) * 8;
  bh8 v;
#pragma unroll
  for (int j = 0; j < 8; ++j) v[j] = (__bf16)tf[cl + j][nl];
  *(bh8*)&xT[((size_t)b * NPIX + n0 + nl) * CDIM + c0 + cl] = v;
}

// ====== 256x128 tile GEMM, K=256 as 4 x BK=64 (r5-proven schedule) ==========
// A single-buffered (32KB), B double-buffered (2x16KB). Staging via
// global_load_lds, conflict-free chunk-XOR swizzle (16B chunk c of row r
// stored at c ^ (r&7); source pre-swizzled). Counted vmcnt(2) per step.
// Epilogue: per m-slice LDS bounce -> full-cacheline coalesced writes.

#define BSP(pb) ((__bf16*)(smem + 32768 + (pb)*16384))

#define STA(kt)                                                                \
  do {                                                                         \
    _Pragma("unroll") for (int i_ = 0; i_ < 4; ++i_) {                         \
      int j_ = i_ * 512 + tid;                                                 \
      int row_ = j_ >> 3, c_ = j_ & 7;                                         \
      int sc_ = c_ ^ (row_ & 7);                                               \
      gload16(Ab + (size_t)row_ * 256 + (kt)*64 + sc_ * 8, As + j_ * 8);       \
    }                                                                          \
  } while (0)

#define STB(kt, pb)                                                            \
  do {                                                                         \
    _Pragma("unroll") for (int i_ = 0; i_ < 2; ++i_) {                         \
      int j_ = i_ * 512 + tid;                                                 \
      int row_ = j_ >> 3, c_ = j_ & 7;                                         \
      int sc_ = c_ ^ (row_ & 7);                                               \
      gload16(Bb + (size_t)row_ * 256 + (kt)*64 + sc_ * 8, BSP(pb) + j_ * 8);  \
    }                                                                          \
  } while (0)

#define COMP(pb)                                                               \
  do {                                                                         \
    _Pragma("unroll") for (int ks_ = 0; ks_ < 2; ++ks_) {                      \
      bh8 a_[4], b_[4];                                                        \
      const int swk_ = (ks_ * 4 + fq) ^ (fr & 7);                              \
      _Pragma("unroll") for (int m_ = 0; m_ < 4; ++m_)                         \
        a_[m_] = *(const bh8*)&As[(wm * 64 + m_ * 16 + fr) * 64 + swk_ * 8];   \
      _Pragma("unroll") for (int n_ = 0; n_ < 4; ++n_)                         \
        b_[n_] = *(const bh8*)&BSP(pb)[(wn * 64 + n_ * 16 + fr) * 64 + swk_ * 8];\
      _Pragma("unroll") for (int m_ = 0; m_ < 4; ++m_)                         \
      _Pragma("unroll") for (int n_ = 0; n_ < 4; ++n_)                         \
        acc[m_][n_] = mfma16(a_[m_], b_[n_], acc[m_][n_]);                     \
    }                                                                          \
  } while (0)

// EPI==0: A = wqkv rows 256..767 (by=0 -> k with exp(), by=1 -> v)
// EPI==1: A = W3[b]; writes f32 out + bias
template <int EPI>
__global__ __launch_bounds__(512, 4) void gemm256(
    const __bf16* __restrict__ A, const __bf16* __restrict__ Bx,
    __bf16* __restrict__ ekmat, __bf16* __restrict__ vmat,
    const float* __restrict__ bias, float* __restrict__ fout) {
  __shared__ __align__(16) char smem[65536];
  __bf16* As = (__bf16*)smem;       // [256 rows][64 k] 32KB
  const int tid = threadIdx.x;
  const int bx = blockIdx.x, by = blockIdx.y, b = blockIdx.z;
  const int lane = tid & 63, wid = tid >> 6;
  const int wm = wid >> 1, wn = wid & 1;
  const int fr = lane & 15, fq = lane >> 4;
  const __bf16* Ab = A + (size_t)((EPI == 0) ? (1 + by) : b) * 65536;
  const __bf16* Bb = Bx + ((size_t)b * NPIX + (size_t)bx * 128) * 256;

  fx4 acc[4][4] = {};

  STB(0, 0); STA(0);
  STB(1, 1); VMWI(2); pbar(); COMP(0); pbar(); STA(1);
  STB(2, 0); VMWI(2); pbar(); COMP(1); pbar(); STA(2);
  STB(3, 1); VMWI(2); pbar(); COMP(0); pbar(); STA(3);
             VMWI(0); pbar(); COMP(1); pbar();

  // ---- epilogue: per m-slice LDS bounce -> full-line coalesced writes
  if (EPI == 0) {
    __bf16* dst = (by == 0) ? ekmat : vmat;
    const size_t dbase = (size_t)b * CDIM * NPIX + (size_t)bx * 128;
    __bf16* Lh = (__bf16*)smem;     // [64][136] pad: 272B rows, 16B aligned
#pragma unroll
    for (int m = 0; m < 4; ++m) {
      __syncthreads();
#pragma unroll
      for (int n = 0; n < 4; ++n)
#pragma unroll
        for (int j = 0; j < 4; ++j) {
          float v = acc[m][n][j];
          if (by == 0) v = __expf(v);
          Lh[(wm * 16 + fq * 4 + j) * 136 + wn * 64 + n * 16 + fr] = (__bf16)v;
        }
      __syncthreads();
#pragma unroll
      for (int it = 0; it < 2; ++it) {
        int u = it * 512 + tid;
        int rr = u >> 4, cc = u & 15;
        int gch = (rr >> 4) * 64 + m * 16 + (rr & 15);
        bh8 val = *(const bh8*)&Lh[rr * 136 + cc * 8];
        *(bh8*)&dst[dbase + (size_t)gch * NPIX + cc * 8] = val;
      }
    }
  } else {
    const size_t obase = (size_t)b * CDIM * NPIX + (size_t)bx * 128;
    float* Ls = (float*)smem;       // [64][132] pad: 528B rows, 16B aligned
#pragma unroll
    for (int m = 0; m < 4; ++m) {
      __syncthreads();
#pragma unroll
      for (int n = 0; n < 4; ++n)
#pragma unroll
        for (int j = 0; j < 4; ++j)
          Ls[(wm * 16 + fq * 4 + j) * 132 + wn * 64 + n * 16 + fr] =
              acc[m][n][j] + bias[wm * 64 + m * 16 + fq * 4 + j];
      __syncthreads();
#pragma unroll
      for (int it = 0; it < 4; ++it) {
        int u = it * 512 + tid;
        int rr = u >> 5, cc = u & 31;
        int gch = (rr >> 4) * 64 + m * 16 + (rr & 15);
        fx4 val = *(const fx4*)&Ls[rr * 132 + cc * 4];
        *(fx4*)&fout[obase + (size_t)gch * NPIX + cc * 4] = val;
      }
    }
  }
}

// ---------------- pass 2: S[d][e] = sum_n ek[d,n] v[e,n]; Zpart per chunk ----
// No atomics, no zero-init needed: every Zpart slot is written exactly once.
__global__ __launch_bounds__(256) void ctx_kernel(const __bf16* __restrict__ ekmat,
                                                  const __bf16* __restrict__ vmat,
                                                  float* __restrict__ S_part,
                                                  float* __restrict__ Zpart) {
  const int chunk = blockIdx.x, h = blockIdx.y, b = blockIdx.z;
  const int t = threadIdx.x;
  const int n0 = chunk * 256;
  __shared__ __bf16 EK[32 * 256];
  __shared__ __bf16 VS[32 * 256];
  __shared__ float zrow[32];

  if (t < 32) zrow[t] = 0.f;
#pragma unroll
  for (int i = 0; i < 4; ++i) {
    int e0 = i * 2048 + t * 8;
    int row = e0 >> 8, col = e0 & 255;
    gload16(ekmat + ((size_t)b * CDIM + h * 32 + row) * NPIX + n0 + col, (void*)(EK + e0));
    gload16(vmat  + ((size_t)b * CDIM + h * 32 + row) * NPIX + n0 + col, (void*)(VS + e0));
  }
  __syncthreads();

  {  // Z partial: thread t sums 32 values of row t>>3 (LDS atomic within block)
    const int row = t >> 3, c0 = (t & 7) * 32;
    float zacc = 0.f;
#pragma unroll
    for (int i = 0; i < 4; ++i) {
      bh8 ev = *(const bh8*)&EK[row * 256 + c0 + i * 8];
#pragma unroll
      for (int j = 0; j < 8; ++j) zacc += (float)ev[j];
    }
    atomicAdd(&zrow[row], zacc);
  }

  const int wid = t >> 6, lane = t & 63, fr = lane & 15, fq = lane >> 4;
  fx4 acc[2][2] = {};
  const int kbase = wid * 64;
#pragma unroll
  for (int kk = 0; kk < 2; ++kk) {
    bh8 a[2], bb[2];
#pragma unroll
    for (int m = 0; m < 2; ++m)
      a[m] = *(const bh8*)&EK[(m * 16 + fr) * 256 + kbase + kk * 32 + fq * 8];
#pragma unroll
    for (int n = 0; n < 2; ++n)
      bb[n] = *(const bh8*)&VS[(n * 16 + fr) * 256 + kbase + kk * 32 + fq * 8];
#pragma unroll
    for (int m = 0; m < 2; ++m)
#pragma unroll
      for (int n = 0; n < 2; ++n) acc[m][n] = mfma16(a[m], bb[n], acc[m][n]);
  }
  __syncthreads();
  float* red = (float*)EK;
#pragma unroll
  for (int m = 0; m < 2; ++m)
#pragma unroll
    for (int n = 0; n < 2; ++n)
#pragma unroll
      for (int j = 0; j < 4; ++j)
        red[wid * 1024 + (m * 16 + fq * 4 + j) * 32 + (n * 16 + fr)] = acc[m][n][j];
  __syncthreads();
  const size_t bh = (size_t)b * 8 + h;
  for (int i = t; i < 1024; i += 256) {
    float s = red[i] + red[1024 + i] + red[2048 + i] + red[3072 + i];
    S_part[(bh * 64 + chunk) * 1024 + i] = s;
  }
  if (t < 32) Zpart[(bh * 64 + chunk) * 32 + t] = zrow[t];
}

// ---------------- pass 2.5: reduce S_part/Zpart over chunks -> ctx -----------
__global__ __launch_bounds__(256) void reduce_ctx(const float* __restrict__ S_part,
                                                  const float* __restrict__ Zpart,
                                                  float* __restrict__ ctx) {
  const int bh = blockIdx.x;
  const int t = threadIdx.x;
  __shared__ float zs[32];
  if (t < 32) {
    float z = 0.f;
    for (int ch = 0; ch < 64; ++ch) z += Zpart[((size_t)bh * 64 + ch) * 32 + t];
    zs[t] = z;
  }
  __syncthreads();
  for (int i = t; i < 1024; i += 256) {
    float s = 0.f;
    for (int ch = 0; ch < 64; ++ch) s += S_part[((size_t)bh * 64 + ch) * 1024 + i];
    ctx[(size_t)bh * 1024 + i] = s / zs[i >> 5];
  }
}

// ---------------- pass 3: W2b[b][oc][h*32+d] = sum_e w_out[oc][h*32+e]*ctx ---
__global__ __launch_bounds__(256) void make_w2(const float* __restrict__ ctx,
                                               const float* __restrict__ w_out,
                                               __bf16* __restrict__ W2b) {
  const int oc = blockIdx.x, b = blockIdx.y, t = threadIdx.x;
  const int h = t >> 5, d = t & 31;
  const float* wrow = w_out + oc * 256 + h * 32;
  const float* crow = ctx + (((size_t)b * 8 + h) * 32 + d) * 32;
  float s = 0.f;
#pragma unroll
  for (int e = 0; e < 32; ++e) s += wrow[e] * crow[e];
  W2b[((size_t)b * 256 + oc) * 256 + t] = (__bf16)s;
}

// ---------------- pass 3.5: W3[b] = W2b[b] (256x256) x Wq (256x256), MFMA ----
// W3[r][t] = sum_o W2b[r][o] * WqT[t][o].  Grid (2,2,8), 256 thr (4 waves).
__global__ __launch_bounds__(256) void make_w3(const __bf16* __restrict__ W2b,
                                               const __bf16* __restrict__ wqT,
                                               __bf16* __restrict__ W3) {
  const int bx = blockIdx.x, by = blockIdx.y, b = blockIdx.z;
  const int lane = threadIdx.x & 63, wid = threadIdx.x >> 6;
  const int wm = wid >> 1, wn = wid & 1;
  const int fr = lane & 15, fq = lane >> 4;
  const __bf16* Ab = W2b + (size_t)b * 65536 + (size_t)(by * 128 + wm * 64) * 256;
  const __bf16* Bb = wqT + (size_t)(bx * 128 + wn * 64) * 256;
  fx4 acc[4][4] = {};
#pragma unroll
  for (int h = 0; h < 8; ++h) {
    bh8 a_[4], b_[4];
#pragma unroll
    for (int m = 0; m < 4; ++m)
      a_[m] = *(const bh8*)(Ab + (size_t)(m * 16 + fr) * 256 + h * 32 + fq * 8);
#pragma unroll
    for (int n = 0; n < 4; ++n)
      b_[n] = *(const bh8*)(Bb + (size_t)(n * 16 + fr) * 256 + h * 32 + fq * 8);
#pragma unroll
    for (int m = 0; m < 4; ++m)
#pragma unroll
      for (int n = 0; n < 4; ++n) acc[m][n] = mfma16(a_[m], b_[n], acc[m][n]);
  }
#pragma unroll
  for (int m = 0; m < 4; ++m)
#pragma unroll
    for (int n = 0; n < 4; ++n) {
      int r0 = by * 128 + wm * 64 + m * 16 + fq * 4;
      int t0 = bx * 128 + wn * 64 + n * 16 + fr;
#pragma unroll
      for (int j = 0; j < 4; ++j)
        W3[(size_t)b * 65536 + (size_t)(r0 + j) * 256 + t0] = (__bf16)acc[m][n][j];
    }
}

extern "C" void kernel_launch(void* const* d_in, const int* in_sizes, int n_in,
                              void* d_out, int out_size, void* d_ws, size_t ws_size,
                              hipStream_t stream) {
  const float* x     = (const float*)d_in[0];
  const float* w_qkv = (const float*)d_in[1];
  const float* w_out = (const float*)d_in[2];
  const float* b_out = (const float*)d_in[3];
  float* out = (float*)d_out;

  char* ws = (char*)d_ws;
  __bf16* xT    = (__bf16*)(ws);                     // 67,108,864
  __bf16* wqb   = (__bf16*)(ws + 67108864ull);       // 393,216
  __bf16* wqT   = (__bf16*)(ws + 67502080ull);       // 131,072
  __bf16* W2b   = (__bf16*)(ws + 67633152ull);       // 1,048,576
  __bf16* W3    = (__bf16*)(ws + 68681728ull);       // 1,048,576
  float*  S_part= (float*) (ws + 69730304ull);       // 16,777,216
  float*  Zpart = (float*) (ws + 86507520ull);       // 524,288
  float*  ctx   = (float*) (ws + 87031808ull);       // 262,144 (end ~87.3 MB)

  // exp(k)/v bf16 scratch lives inside d_out (fully overwritten by final GEMM)
  __bf16* ekmat = (__bf16*)d_out;                      // [8][256][NPIX] 64 MiB
  __bf16* vmat  = ekmat + (size_t)BATCH * CDIM * NPIX; // next 64 MiB

  conv_w<<<768, 256, 0, stream>>>(w_qkv, wqb, MQKV * CDIM);
  transpose_wq<<<dim3(8, 8), 256, 0, stream>>>(w_qkv, wqT);
  transpose_x<<<dim3(NPIX / 32, CDIM / 64, BATCH), 256, 0, stream>>>(x, xT);
  gemm256<0><<<dim3(NPIX / 128, 2, BATCH), 512, 0, stream>>>(
      wqb, xT, ekmat, vmat, nullptr, nullptr);
  ctx_kernel<<<dim3(64, 8, BATCH), 256, 0, stream>>>(ekmat, vmat, S_part, Zpart);
  reduce_ctx<<<64, 256, 0, stream>>>(S_part, Zpart, ctx);
  make_w2<<<dim3(256, BATCH), 256, 0, stream>>>(ctx, w_out, W2b);
  make_w3<<<dim3(2, 2, BATCH), 256, 0, stream>>>(W2b, wqT, W3);
  gemm256<1><<<dim3(NPIX / 128, 1, BATCH), 512, 0, stream>>>(
      W3, xT, nullptr, nullptr, b_out, out);
}

// Round 9
// 192.919 us; speedup vs baseline: 1.4066x; 1.0343x over previous
//
#include <hip/hip_runtime.h>
#include <hip/hip_bf16.h>
#include <cstdint>

#define NPIX 16384   // h*w = 128*128
#define BATCH 8
#define CDIM 256

typedef __bf16 bh8 __attribute__((ext_vector_type(8)));
typedef __bf16 bh4 __attribute__((ext_vector_type(4)));
typedef float  fx4 __attribute__((ext_vector_type(4)));

__device__ __forceinline__ void gload16(const void* g, void* l) {
  __builtin_amdgcn_global_load_lds(
      (const __attribute__((address_space(1))) uint32_t*)g,
      (__attribute__((address_space(3))) uint32_t*)l, 16, 0, 0);
}

__device__ __forceinline__ fx4 mfma16(bh8 a, bh8 b, fx4 c) {
  return __builtin_amdgcn_mfma_f32_16x16x32_bf16(a, b, c, 0, 0, 0);
}

__device__ __forceinline__ void pbar() {
  asm volatile("" ::: "memory");
  __builtin_amdgcn_s_barrier();
  asm volatile("" ::: "memory");
}
#define VMWI(n) asm volatile("s_waitcnt vmcnt(" #n ")" ::: "memory")

// -------- pass 0a: convert w_qkv rows 256..767 (k,v) f32 -> bf16 ------------
__global__ void conv_w(const float* __restrict__ w, __bf16* __restrict__ wb, int n) {
  int i = blockIdx.x * 256 + threadIdx.x;
  if (i < n) wb[i] = (__bf16)w[i];
}

// -------- pass 0a': WqT[t][o] = Wq[o][t] (first 256 rows), bf16 -------------
__global__ __launch_bounds__(256) void transpose_wq(const float* __restrict__ w_qkv,
                                                    __bf16* __restrict__ wqT) {
  __shared__ float tile[32][33];
  const int t0 = blockIdx.x * 32, o0 = blockIdx.y * 32;
  const int tx = threadIdx.x & 31, ty = threadIdx.x >> 5;
#pragma unroll
  for (int j = 0; j < 4; ++j) {
    int r = ty * 4 + j;  // local o
    tile[r][tx] = w_qkv[(size_t)(o0 + r) * 256 + t0 + tx];
  }
  __syncthreads();
#pragma unroll
  for (int j = 0; j < 4; ++j) {
    int tl = ty * 4 + j; // local t
    wqT[(size_t)(t0 + tl) * 256 + o0 + tx] = (__bf16)tile[tx][tl];
  }
}

// -------- pass 0b: x [b][256][NPIX] f32 -> xT [b][NPIX][256] bf16 -----------
__global__ __launch_bounds__(256) void transpose_x(const float* __restrict__ x,
                                                   __bf16* __restrict__ xT) {
  __shared__ float tf[64][33];
  const int n0 = blockIdx.x * 32, c0 = blockIdx.y * 64, b = blockIdx.z;
  const int u = threadIdx.x;
  const int tx = u & 31, tg = u >> 5;
#pragma unroll
  for (int j = 0; j < 8; ++j) {
    int r = tg * 8 + j;
    tf[r][tx] = x[((size_t)b * CDIM + c0 + r) * NPIX + n0 + tx];
  }
  __syncthreads();
  const int nl = u >> 3, cl = (u & 7) * 8;
  bh8 v;
#pragma unroll
  for (int j = 0; j < 8; ++j) v[j] = (__bf16)tf[cl + j][nl];
  *(bh8*)&xT[((size_t)b * NPIX + n0 + nl) * CDIM + c0 + cl] = v;
}

// ====== 256x128 tile GEMM, K=256 as 4 x BK=64 (r5-proven schedule) ==========
// EPI==0: A rows = matched k||v for head-group hg=by*4; epilogue computes
//         per-head S (32x32 over this block's 128 px) + Z partials in-LDS.
// EPI==1: A = W3[b]; writes f32 out + bias via coalescing LDS bounce.

#define BSP(pb) ((__bf16*)(smem + 32768 + (pb)*16384))

#define STA(kt)                                                                \
  do {                                                                         \
    _Pragma("unroll") for (int i_ = 0; i_ < 4; ++i_) {                         \
      int j_ = i_ * 512 + tid;                                                 \
      int row_ = j_ >> 3, c_ = j_ & 7;                                         \
      int sc_ = c_ ^ (row_ & 7);                                               \
      const __bf16* sb_;                                                       \
      if (EPI == 0) sb_ = (i_ < 2) ? Abk + (size_t)row_ * 256                  \
                                   : Abv + (size_t)(row_ - 128) * 256;         \
      else          sb_ = Ab + (size_t)row_ * 256;                             \
      gload16(sb_ + (kt)*64 + sc_ * 8, As + j_ * 8);                           \
    }                                                                          \
  } while (0)

#define STB(kt, pb)                                                            \
  do {                                                                         \
    _Pragma("unroll") for (int i_ = 0; i_ < 2; ++i_) {                         \
      int j_ = i_ * 512 + tid;                                                 \
      int row_ = j_ >> 3, c_ = j_ & 7;                                         \
      int sc_ = c_ ^ (row_ & 7);                                               \
      gload16(Bb + (size_t)row_ * 256 + (kt)*64 + sc_ * 8, BSP(pb) + j_ * 8);  \
    }                                                                          \
  } while (0)

#define COMP(pb)                                                               \
  do {                                                                         \
    _Pragma("unroll") for (int ks_ = 0; ks_ < 2; ++ks_) {                      \
      bh8 a_[4], b_[4];                                                        \
      const int swk_ = (ks_ * 4 + fq) ^ (fr & 7);                              \
      _Pragma("unroll") for (int m_ = 0; m_ < 4; ++m_)                         \
        a_[m_] = *(const bh8*)&As[(wm * 64 + m_ * 16 + fr) * 64 + swk_ * 8];   \
      _Pragma("unroll") for (int n_ = 0; n_ < 4; ++n_)                         \
        b_[n_] = *(const bh8*)&BSP(pb)[(wn * 64 + n_ * 16 + fr) * 64 + swk_ * 8];\
      _Pragma("unroll") for (int m_ = 0; m_ < 4; ++m_)                         \
      _Pragma("unroll") for (int n_ = 0; n_ < 4; ++n_)                         \
        acc[m_][n_] = mfma16(a_[m_], b_[n_], acc[m_][n_]);                     \
    }                                                                          \
  } while (0)

template <int EPI>
__global__ __launch_bounds__(512, 4) void gemm256(
    const __bf16* __restrict__ A, const __bf16* __restrict__ Bx,
    float* __restrict__ S_part, float* __restrict__ Zpart,
    const float* __restrict__ bias, float* __restrict__ fout) {
  __shared__ __align__(16) char smem[66560];
  __bf16* As = (__bf16*)smem;       // [256 rows][64 k] 32KB
  const int tid = threadIdx.x;
  const int bx = blockIdx.x, by = blockIdx.y, b = blockIdx.z;
  const int lane = tid & 63, wid = tid >> 6;
  const int wm = wid >> 1, wn = wid & 1;
  const int fr = lane & 15, fq = lane >> 4;
  const int hg = by * 4;  // EPI==0 head-group
  // wqb holds w_qkv rows 256..767: k at [0,256), v at [256,512)
  const __bf16* Abk = A + (size_t)(hg * 32) * 256;
  const __bf16* Abv = A + (size_t)(256 + hg * 32) * 256;
  const __bf16* Ab  = A + (size_t)b * 65536;
  const __bf16* Bb = Bx + ((size_t)b * NPIX + (size_t)bx * 128) * 256;

  fx4 acc[4][4] = {};

  STB(0, 0); STA(0);
  STB(1, 1); VMWI(2); pbar(); COMP(0); pbar(); STA(1);
  STB(2, 0); VMWI(2); pbar(); COMP(1); pbar(); STA(2);
  STB(3, 1); VMWI(2); pbar(); COMP(0); pbar(); STA(3);
             VMWI(0); pbar(); COMP(1); pbar();

  if (EPI == 0) {
    // ---- epilogue A: bounce exp(k) [128x128] and v [128x128] into LDS
    // (chunk-XOR swizzled), then per-head S = ek·v^T over 128 px + Z rows.
    float* zrow = (float*)(smem + 65536);  // 128 floats
    if (tid < 128) zrow[tid] = 0.f;
#pragma unroll
    for (int m = 0; m < 4; ++m)
#pragma unroll
      for (int n = 0; n < 4; ++n)
#pragma unroll
        for (int j = 0; j < 4; ++j) {
          int r = wm * 64 + m * 16 + fq * 4 + j;   // 0..255 (k then v)
          int px = wn * 64 + n * 16 + fr;          // 0..127
          int pc = px >> 3;
          if (wm < 2) {                            // k rows -> exp -> Lk @0
            int byo = r * 256 + ((pc ^ (r & 7)) << 4) + (px & 7) * 2;
            *(__bf16*)(smem + byo) = (__bf16)__expf(acc[m][n][j]);
          } else {                                 // v rows -> Lv @32768
            int r2 = r - 128;
            int byo = r2 * 256 + ((pc ^ (r2 & 7)) << 4) + (px & 7) * 2;
            *(__bf16*)(smem + 32768 + byo) = (__bf16)acc[m][n][j];
          }
        }
    __syncthreads();
    {  // Z: 4 threads per row, 32 px each
      int r = tid >> 2, c0 = (tid & 3) * 32;
      float za = 0.f;
#pragma unroll
      for (int i2 = 0; i2 < 4; ++i2) {
        int px0 = c0 + i2 * 8;
        int pc = px0 >> 3;
        bh8 ev = *(const bh8*)(smem + r * 256 + ((pc ^ (r & 7)) << 4));
#pragma unroll
        for (int jj = 0; jj < 8; ++jj) za += (float)ev[jj];
      }
      atomicAdd(&zrow[r], za);
    }
    // S: 16 tasks (4 heads x 4 quadrants) over 8 waves, 2 tasks/wave
    fx4 sac0 = {}, sac1 = {};
#pragma unroll
    for (int t2 = 0; t2 < 2; ++t2) {
      int tk = wid * 2 + t2;
      int hl = tk >> 2, quad = tk & 3;
      int drow = (quad >> 1) * 16, erow = (quad & 1) * 16;
      fx4 sac = {};
#pragma unroll
      for (int kt2 = 0; kt2 < 4; ++kt2) {
        int ra = hl * 32 + drow + fr;
        int rb = hl * 32 + erow + fr;
        int pc = kt2 * 4 + fq;
        bh8 af = *(const bh8*)(smem + ra * 256 + ((pc ^ (ra & 7)) << 4));
        bh8 bf = *(const bh8*)(smem + 32768 + rb * 256 + ((pc ^ (rb & 7)) << 4));
        sac = mfma16(af, bf, sac);
      }
      if (t2 == 0) sac0 = sac; else sac1 = sac;
    }
    __syncthreads();  // zrow complete
#pragma unroll
    for (int t2 = 0; t2 < 2; ++t2) {
      int tk = wid * 2 + t2;
      int hl = tk >> 2, quad = tk & 3;
      int drow = (quad >> 1) * 16, erow = (quad & 1) * 16;
      float* sp = S_part + ((size_t)((b * 8 + hg + hl) * 128 + bx)) * 1024;
      fx4 sv = (t2 == 0) ? sac0 : sac1;
#pragma unroll
      for (int j = 0; j < 4; ++j)
        sp[(drow + fq * 4 + j) * 32 + erow + fr] = sv[j];
    }
    if (tid < 128) {
      int head = hg + (tid >> 5);
      Zpart[((size_t)(b * 8 + head) * 128 + bx) * 32 + (tid & 31)] = zrow[tid];
    }
  } else {
    // ---- epilogue B: per m-slice LDS bounce -> full-line coalesced writes
    const size_t obase = (size_t)b * CDIM * NPIX + (size_t)bx * 128;
    float* Ls = (float*)smem;       // [64][132] pad
#pragma unroll
    for (int m = 0; m < 4; ++m) {
      __syncthreads();
#pragma unroll
      for (int n = 0; n < 4; ++n)
#pragma unroll
        for (int j = 0; j < 4; ++j)
          Ls[(wm * 16 + fq * 4 + j) * 132 + wn * 64 + n * 16 + fr] =
              acc[m][n][j] + bias[wm * 64 + m * 16 + fq * 4 + j];
      __syncthreads();
#pragma unroll
      for (int it = 0; it < 4; ++it) {
        int u = it * 512 + tid;
        int rr = u >> 5, cc = u & 31;
        int gch = (rr >> 4) * 64 + m * 16 + (rr & 15);
        fx4 val = *(const fx4*)&Ls[rr * 132 + cc * 4];
        *(fx4*)&fout[obase + (size_t)gch * NPIX + cc * 4] = val;
      }
    }
  }
}

// -------- pass 2.5: reduce S_part/Zpart over 128 chunks -> ctx --------------
__global__ __launch_bounds__(256) void reduce_ctx(const float* __restrict__ S_part,
                                                  const float* __restrict__ Zpart,
                                                  float* __restrict__ ctx) {
  const int bh = blockIdx.x;  // 64
  const int t = threadIdx.x;
  __shared__ float zs[32];
  if (t < 32) {
    float z = 0.f;
    for (int ch = 0; ch < 128; ++ch) z += Zpart[((size_t)bh * 128 + ch) * 32 + t];
    zs[t] = z;
  }
  __syncthreads();
  for (int i = t; i < 1024; i += 256) {
    float s = 0.f;
    for (int ch = 0; ch < 128; ++ch) s += S_part[((size_t)bh * 128 + ch) * 1024 + i];
    ctx[(size_t)bh * 1024 + i] = s / zs[i >> 5];
  }
}

// -------- pass 3: W2b[b][oc][h*32+d] = sum_e w_out[oc][h*32+e]*ctx ----------
__global__ __launch_bounds__(256) void make_w2(const float* __restrict__ ctx,
                                               const float* __restrict__ w_out,
                                               __bf16* __restrict__ W2b) {
  const int oc = blockIdx.x, b = blockIdx.y, t = threadIdx.x;
  const int h = t >> 5, d = t & 31;
  const float* wrow = w_out + oc * 256 + h * 32;
  const float* crow = ctx + (((size_t)b * 8 + h) * 32 + d) * 32;
  float s = 0.f;
#pragma unroll
  for (int e = 0; e < 32; ++e) s += wrow[e] * crow[e];
  W2b[((size_t)b * 256 + oc) * 256 + t] = (__bf16)s;
}

// -------- pass 3.5: W3[b] = W2b[b] x Wq (via WqT), MFMA ---------------------
__global__ __launch_bounds__(256) void make_w3(const __bf16* __restrict__ W2b,
                                               const __bf16* __restrict__ wqT,
                                               __bf16* __restrict__ W3) {
  const int bx = blockIdx.x, by = blockIdx.y, b = blockIdx.z;
  const int lane = threadIdx.x & 63, wid = threadIdx.x >> 6;
  const int wm = wid >> 1, wn = wid & 1;
  const int fr = lane & 15, fq = lane >> 4;
  const __bf16* Ab = W2b + (size_t)b * 65536 + (size_t)(by * 128 + wm * 64) * 256;
  const __bf16* Bb = wqT + (size_t)(bx * 128 + wn * 64) * 256;
  fx4 acc[4][4] = {};
#pragma unroll
  for (int h = 0; h < 8; ++h) {
    bh8 a_[4], b_[4];
#pragma unroll
    for (int m = 0; m < 4; ++m)
      a_[m] = *(const bh8*)(Ab + (size_t)(m * 16 + fr) * 256 + h * 32 + fq * 8);
#pragma unroll
    for (int n = 0; n < 4; ++n)
      b_[n] = *(const bh8*)(Bb + (size_t)(n * 16 + fr) * 256 + h * 32 + fq * 8);
#pragma unroll
    for (int m = 0; m < 4; ++m)
#pragma unroll
      for (int n = 0; n < 4; ++n) acc[m][n] = mfma16(a_[m], b_[n], acc[m][n]);
  }
#pragma unroll
  for (int m = 0; m < 4; ++m)
#pragma unroll
    for (int n = 0; n < 4; ++n) {
      int r0 = by * 128 + wm * 64 + m * 16 + fq * 4;
      int t0 = bx * 128 + wn * 64 + n * 16 + fr;
#pragma unroll
      for (int j = 0; j < 4; ++j)
        W3[(size_t)b * 65536 + (size_t)(r0 + j) * 256 + t0] = (__bf16)acc[m][n][j];
    }
}

extern "C" void kernel_launch(void* const* d_in, const int* in_sizes, int n_in,
                              void* d_out, int out_size, void* d_ws, size_t ws_size,
                              hipStream_t stream) {
  const float* x     = (const float*)d_in[0];
  const float* w_qkv = (const float*)d_in[1];
  const float* w_out = (const float*)d_in[2];
  const float* b_out = (const float*)d_in[3];
  float* out = (float*)d_out;

  char* ws = (char*)d_ws;
  __bf16* xT    = (__bf16*)(ws);                     // 67,108,864
  __bf16* wqb   = (__bf16*)(ws + 67108864ull);       // 262,144 (k,v rows only)
  __bf16* wqT   = (__bf16*)(ws + 67371008ull);       // 131,072
  __bf16* W2b   = (__bf16*)(ws + 67502080ull);       // 1,048,576
  __bf16* W3    = (__bf16*)(ws + 68550656ull);       // 1,048,576
  float*  S_part= (float*) (ws + 69599232ull);       // 33,554,432
  float*  Zpart = (float*) (ws + 103153664ull);      // 1,048,576
  float*  ctx   = (float*) (ws + 104202240ull);      // 262,144 (end ~99.7 MB)

  conv_w<<<512, 256, 0, stream>>>(w_qkv + 256 * 256, wqb, 512 * 256);
  transpose_wq<<<dim3(8, 8), 256, 0, stream>>>(w_qkv, wqT);
  transpose_x<<<dim3(NPIX / 32, CDIM / 64, BATCH), 256, 0, stream>>>(x, xT);
  gemm256<0><<<dim3(NPIX / 128, 2, BATCH), 512, 0, stream>>>(
      wqb, xT, S_part, Zpart, nullptr, nullptr);
  reduce_ctx<<<64, 256, 0, stream>>>(S_part, Zpart, ctx);
  make_w2<<<dim3(256, BATCH), 256, 0, stream>>>(ctx, w_out, W2b);
  make_w3<<<dim3(2, 2, BATCH), 256, 0, stream>>>(W2b, wqT, W3);
  gemm256<1><<<dim3(NPIX / 128, 1, BATCH), 512, 0, stream>>>(
      W3, xT, nullptr, nullptr, b_out, out);
}

// Round 10
// 179.997 us; speedup vs baseline: 1.5076x; 1.0718x over previous
//
#include <hip/hip_runtime.h>
#include <hip/hip_bf16.h>
#include <cstdint>

#define NPIX 16384   // h*w = 128*128
#define BATCH 8
#define CDIM 256

typedef __bf16 bh8 __attribute__((ext_vector_type(8)));
typedef __bf16 bh4 __attribute__((ext_vector_type(4)));
typedef float  fx4 __attribute__((ext_vector_type(4)));

__device__ __forceinline__ void gload16(const void* g, void* l) {
  __builtin_amdgcn_global_load_lds(
      (const __attribute__((address_space(1))) uint32_t*)g,
      (__attribute__((address_space(3))) uint32_t*)l, 16, 0, 0);
}

__device__ __forceinline__ fx4 mfma16(bh8 a, bh8 b, fx4 c) {
  return __builtin_amdgcn_mfma_f32_16x16x32_bf16(a, b, c, 0, 0, 0);
}

__device__ __forceinline__ void pbar() {
  asm volatile("" ::: "memory");
  __builtin_amdgcn_s_barrier();
  asm volatile("" ::: "memory");
}
#define VMWI(n) asm volatile("s_waitcnt vmcnt(" #n ")" ::: "memory")

// -------- pass 0a: convert w_qkv rows 256..767 (k,v) f32 -> bf16 ------------
__global__ void conv_w(const float* __restrict__ w, __bf16* __restrict__ wb, int n) {
  int i = blockIdx.x * 256 + threadIdx.x;
  if (i < n) wb[i] = (__bf16)w[i];
}

// -------- pass 0a': WqT[t][o] = Wq[o][t] (first 256 rows), bf16 -------------
__global__ __launch_bounds__(256) void transpose_wq(const float* __restrict__ w_qkv,
                                                    __bf16* __restrict__ wqT) {
  __shared__ float tile[32][33];
  const int t0 = blockIdx.x * 32, o0 = blockIdx.y * 32;
  const int tx = threadIdx.x & 31, ty = threadIdx.x >> 5;
#pragma unroll
  for (int j = 0; j < 4; ++j) {
    int r = ty * 4 + j;  // local o
    tile[r][tx] = w_qkv[(size_t)(o0 + r) * 256 + t0 + tx];
  }
  __syncthreads();
#pragma unroll
  for (int j = 0; j < 4; ++j) {
    int tl = ty * 4 + j; // local t
    wqT[(size_t)(t0 + tl) * 256 + o0 + tx] = (__bf16)tile[tx][tl];
  }
}

// -------- pass 0b: x [b][256][NPIX] f32 -> xT [b][NPIX][256] bf16 -----------
// 64c x 64n tiles: 256B-contiguous reads, full-128B-line bh8 writes.
__global__ __launch_bounds__(256) void transpose_x(const float* __restrict__ x,
                                                   __bf16* __restrict__ xT) {
  __shared__ float tf[64][68];
  const int n0 = blockIdx.x * 64, c0 = blockIdx.y * 64, b = blockIdx.z;
  const int u = threadIdx.x;
#pragma unroll
  for (int i = 0; i < 4; ++i) {
    int j = i * 256 + u;
    int r = j >> 4, q = j & 15;  // r: local c, q: px quad
    *(fx4*)&tf[r][q * 4] =
        *(const fx4*)&x[((size_t)b * CDIM + c0 + r) * NPIX + n0 + q * 4];
  }
  __syncthreads();
  const int nl = u >> 2, cq = (u & 3) * 16;
#pragma unroll
  for (int w = 0; w < 2; ++w) {
    bh8 v;
#pragma unroll
    for (int j = 0; j < 8; ++j) v[j] = (__bf16)tf[cq + w * 8 + j][nl];
    *(bh8*)&xT[((size_t)b * NPIX + n0 + nl) * CDIM + c0 + cq + w * 8] = v;
  }
}

// ====== 256x128 tile GEMM, K=256 as 4 x BK=64 (r5-proven schedule) ==========
// EPI==0: A rows = matched k||v for head-group hg; epilogue computes per-head
//         S (32x32 over this block's 128 px) + Z partials in-LDS.
//         Grid (2,128,8): by=blockIdx.x so the two head-groups sharing a
//         B-tile are adjacent in dispatch order -> same-XCD L2 reuse.
// EPI==1: A = W3[b]; writes f32 out + bias via coalescing LDS bounce.

#define BSP(pb) ((__bf16*)(smem + 32768 + (pb)*16384))

#define STA(kt)                                                                \
  do {                                                                         \
    _Pragma("unroll") for (int i_ = 0; i_ < 4; ++i_) {                         \
      int j_ = i_ * 512 + tid;                                                 \
      int row_ = j_ >> 3, c_ = j_ & 7;                                         \
      int sc_ = c_ ^ (row_ & 7);                                               \
      const __bf16* sb_;                                                       \
      if (EPI == 0) sb_ = (i_ < 2) ? Abk + (size_t)row_ * 256                  \
                                   : Abv + (size_t)(row_ - 128) * 256;         \
      else          sb_ = Ab + (size_t)row_ * 256;                             \
      gload16(sb_ + (kt)*64 + sc_ * 8, As + j_ * 8);                           \
    }                                                                          \
  } while (0)

#define STB(kt, pb)                                                            \
  do {                                                                         \
    _Pragma("unroll") for (int i_ = 0; i_ < 2; ++i_) {                         \
      int j_ = i_ * 512 + tid;                                                 \
      int row_ = j_ >> 3, c_ = j_ & 7;                                         \
      int sc_ = c_ ^ (row_ & 7);                                               \
      gload16(Bb + (size_t)row_ * 256 + (kt)*64 + sc_ * 8, BSP(pb) + j_ * 8);  \
    }                                                                          \
  } while (0)

#define COMP(pb)                                                               \
  do {                                                                         \
    _Pragma("unroll") for (int ks_ = 0; ks_ < 2; ++ks_) {                      \
      bh8 a_[4], b_[4];                                                        \
      const int swk_ = (ks_ * 4 + fq) ^ (fr & 7);                              \
      _Pragma("unroll") for (int m_ = 0; m_ < 4; ++m_)                         \
        a_[m_] = *(const bh8*)&As[(wm * 64 + m_ * 16 + fr) * 64 + swk_ * 8];   \
      _Pragma("unroll") for (int n_ = 0; n_ < 4; ++n_)                         \
        b_[n_] = *(const bh8*)&BSP(pb)[(wn * 64 + n_ * 16 + fr) * 64 + swk_ * 8];\
      _Pragma("unroll") for (int m_ = 0; m_ < 4; ++m_)                         \
      _Pragma("unroll") for (int n_ = 0; n_ < 4; ++n_)                         \
        acc[m_][n_] = mfma16(a_[m_], b_[n_], acc[m_][n_]);                     \
    }                                                                          \
  } while (0)

template <int EPI>
__global__ __launch_bounds__(512, 4) void gemm256(
    const __bf16* __restrict__ A, const __bf16* __restrict__ Bx,
    float* __restrict__ S_part, float* __restrict__ Zpart,
    const float* __restrict__ bias, float* __restrict__ fout) {
  __shared__ __align__(16) char smem[66560];
  __bf16* As = (__bf16*)smem;       // [256 rows][64 k] 32KB
  const int tid = threadIdx.x;
  const int bx = (EPI == 0) ? blockIdx.y : blockIdx.x;
  const int by = (EPI == 0) ? blockIdx.x : blockIdx.y;
  const int b = blockIdx.z;
  const int lane = tid & 63, wid = tid >> 6;
  const int wm = wid >> 1, wn = wid & 1;
  const int fr = lane & 15, fq = lane >> 4;
  const int hg = by * 4;  // EPI==0 head-group
  // wqb holds w_qkv rows 256..767: k at [0,256), v at [256,512)
  const __bf16* Abk = A + (size_t)(hg * 32) * 256;
  const __bf16* Abv = A + (size_t)(256 + hg * 32) * 256;
  const __bf16* Ab  = A + (size_t)b * 65536;
  const __bf16* Bb = Bx + ((size_t)b * NPIX + (size_t)bx * 128) * 256;

  fx4 acc[4][4] = {};

  STB(0, 0); STA(0);
  STB(1, 1); VMWI(2); pbar(); COMP(0); pbar(); STA(1);
  STB(2, 0); VMWI(2); pbar(); COMP(1); pbar(); STA(2);
  STB(3, 1); VMWI(2); pbar(); COMP(0); pbar(); STA(3);
             VMWI(0); pbar(); COMP(1); pbar();

  if (EPI == 0) {
    // ---- epilogue A: bounce exp(k) [128x128] and v [128x128] into LDS
    // (chunk-XOR swizzled), then per-head S = ek·v^T over 128 px + Z rows.
    float* zrow = (float*)(smem + 65536);  // 128 floats
    if (tid < 128) zrow[tid] = 0.f;
#pragma unroll
    for (int m = 0; m < 4; ++m)
#pragma unroll
      for (int n = 0; n < 4; ++n)
#pragma unroll
        for (int j = 0; j < 4; ++j) {
          int r = wm * 64 + m * 16 + fq * 4 + j;   // 0..255 (k then v)
          int px = wn * 64 + n * 16 + fr;          // 0..127
          int pc = px >> 3;
          if (wm < 2) {                            // k rows -> exp -> Lk @0
            int byo = r * 256 + ((pc ^ (r & 7)) << 4) + (px & 7) * 2;
            *(__bf16*)(smem + byo) = (__bf16)__expf(acc[m][n][j]);
          } else {                                 // v rows -> Lv @32768
            int r2 = r - 128;
            int byo = r2 * 256 + ((pc ^ (r2 & 7)) << 4) + (px & 7) * 2;
            *(__bf16*)(smem + 32768 + byo) = (__bf16)acc[m][n][j];
          }
        }
    __syncthreads();
    {  // Z: 4 threads per row, 32 px each
      int r = tid >> 2, c0 = (tid & 3) * 32;
      float za = 0.f;
#pragma unroll
      for (int i2 = 0; i2 < 4; ++i2) {
        int px0 = c0 + i2 * 8;
        int pc = px0 >> 3;
        bh8 ev = *(const bh8*)(smem + r * 256 + ((pc ^ (r & 7)) << 4));
#pragma unroll
        for (int jj = 0; jj < 8; ++jj) za += (float)ev[jj];
      }
      atomicAdd(&zrow[r], za);
    }
    // S: 16 tasks (4 heads x 4 quadrants) over 8 waves, 2 tasks/wave
    fx4 sac0 = {}, sac1 = {};
#pragma unroll
    for (int t2 = 0; t2 < 2; ++t2) {
      int tk = wid * 2 + t2;
      int hl = tk >> 2, quad = tk & 3;
      int drow = (quad >> 1) * 16, erow = (quad & 1) * 16;
      fx4 sac = {};
#pragma unroll
      for (int kt2 = 0; kt2 < 4; ++kt2) {
        int ra = hl * 32 + drow + fr;
        int rb = hl * 32 + erow + fr;
        int pc = kt2 * 4 + fq;
        bh8 af = *(const bh8*)(smem + ra * 256 + ((pc ^ (ra & 7)) << 4));
        bh8 bf = *(const bh8*)(smem + 32768 + rb * 256 + ((pc ^ (rb & 7)) << 4));
        sac = mfma16(af, bf, sac);
      }
      if (t2 == 0) sac0 = sac; else sac1 = sac;
    }
    __syncthreads();  // zrow complete
#pragma unroll
    for (int t2 = 0; t2 < 2; ++t2) {
      int tk = wid * 2 + t2;
      int hl = tk >> 2, quad = tk & 3;
      int drow = (quad >> 1) * 16, erow = (quad & 1) * 16;
      float* sp = S_part + ((size_t)((b * 8 + hg + hl) * 128 + bx)) * 1024;
      fx4 sv = (t2 == 0) ? sac0 : sac1;
#pragma unroll
      for (int j = 0; j < 4; ++j)
        sp[(drow + fq * 4 + j) * 32 + erow + fr] = sv[j];
    }
    if (tid < 128) {
      int head = hg + (tid >> 5);
      Zpart[((size_t)(b * 8 + head) * 128 + bx) * 32 + (tid & 31)] = zrow[tid];
    }
  } else {
    // ---- epilogue B: per m-slice LDS bounce -> full-line coalesced writes
    const size_t obase = (size_t)b * CDIM * NPIX + (size_t)bx * 128;
    float* Ls = (float*)smem;       // [64][132] pad
#pragma unroll
    for (int m = 0; m < 4; ++m) {
      __syncthreads();
#pragma unroll
      for (int n = 0; n < 4; ++n)
#pragma unroll
        for (int j = 0; j < 4; ++j)
          Ls[(wm * 16 + fq * 4 + j) * 132 + wn * 64 + n * 16 + fr] =
              acc[m][n][j] + bias[wm * 64 + m * 16 + fq * 4 + j];
      __syncthreads();
#pragma unroll
      for (int it = 0; it < 4; ++it) {
        int u = it * 512 + tid;
        int rr = u >> 5, cc = u & 31;
        int gch = (rr >> 4) * 64 + m * 16 + (rr & 15);
        fx4 val = *(const fx4*)&Ls[rr * 132 + cc * 4];
        *(fx4*)&fout[obase + (size_t)gch * NPIX + cc * 4] = val;
      }
    }
  }
}

// -------- pass 2.5: reduce S_part/Zpart over 128 chunks -> ctx --------------
// grid (4 segs, 64 bh): 256 blocks for full-GPU BW.
__global__ __launch_bounds__(256) void reduce_ctx(const float* __restrict__ S_part,
                                                  const float* __restrict__ Zpart,
                                                  float* __restrict__ ctx) {
  const int seg = blockIdx.x;  // 0..3
  const int bh = blockIdx.y;   // 0..63
  const int t = threadIdx.x;
  __shared__ float zs[8];
  if (t < 8) zs[t] = 0.f;
  __syncthreads();
  {
    int row = seg * 8 + (t >> 5);  // global d-row handled by this block
    float z = 0.f;
    for (int ch = (t & 31); ch < 128; ch += 32)
      z += Zpart[((size_t)bh * 128 + ch) * 32 + row];
    atomicAdd(&zs[t >> 5], z);
  }
  __syncthreads();
  const int i = seg * 256 + t;
  float s = 0.f;
  for (int ch = 0; ch < 128; ++ch) s += S_part[((size_t)bh * 128 + ch) * 1024 + i];
  ctx[(size_t)bh * 1024 + i] = s / zs[t >> 5];
}

// -------- pass 3: W2b[b][oc][h*32+d] = sum_e w_out[oc][h*32+e]*ctx ----------
__global__ __launch_bounds__(256) void make_w2(const float* __restrict__ ctx,
                                               const float* __restrict__ w_out,
                                               __bf16* __restrict__ W2b) {
  const int oc = blockIdx.x, b = blockIdx.y, t = threadIdx.x;
  const int h = t >> 5, d = t & 31;
  const float* wrow = w_out + oc * 256 + h * 32;
  const float* crow = ctx + (((size_t)b * 8 + h) * 32 + d) * 32;
  float s = 0.f;
#pragma unroll
  for (int e = 0; e < 32; ++e) s += wrow[e] * crow[e];
  W2b[((size_t)b * 256 + oc) * 256 + t] = (__bf16)s;
}

// -------- pass 3.5: W3[b] = W2b[b] x Wq (via WqT), MFMA ---------------------
__global__ __launch_bounds__(256) void make_w3(const __bf16* __restrict__ W2b,
                                               const __bf16* __restrict__ wqT,
                                               __bf16* __restrict__ W3) {
  const int bx = blockIdx.x, by = blockIdx.y, b = blockIdx.z;
  const int lane = threadIdx.x & 63, wid = threadIdx.x >> 6;
  const int wm = wid >> 1, wn = wid & 1;
  const int fr = lane & 15, fq = lane >> 4;
  const __bf16* Ab = W2b + (size_t)b * 65536 + (size_t)(by * 128 + wm * 64) * 256;
  const __bf16* Bb = wqT + (size_t)(bx * 128 + wn * 64) * 256;
  fx4 acc[4][4] = {};
#pragma unroll
  for (int h = 0; h < 8; ++h) {
    bh8 a_[4], b_[4];
#pragma unroll
    for (int m = 0; m < 4; ++m)
      a_[m] = *(const bh8*)(Ab + (size_t)(m * 16 + fr) * 256 + h * 32 + fq * 8);
#pragma unroll
    for (int n = 0; n < 4; ++n)
      b_[n] = *(const bh8*)(Bb + (size_t)(n * 16 + fr) * 256 + h * 32 + fq * 8);
#pragma unroll
    for (int m = 0; m < 4; ++m)
#pragma unroll
      for (int n = 0; n < 4; ++n) acc[m][n] = mfma16(a_[m], b_[n], acc[m][n]);
  }
#pragma unroll
  for (int m = 0; m < 4; ++m)
#pragma unroll
    for (int n = 0; n < 4; ++n) {
      int r0 = by * 128 + wm * 64 + m * 16 + fq * 4;
      int t0 = bx * 128 + wn * 64 + n * 16 + fr;
#pragma unroll
      for (int j = 0; j < 4; ++j)
        W3[(size_t)b * 65536 + (size_t)(r0 + j) * 256 + t0] = (__bf16)acc[m][n][j];
    }
}

extern "C" void kernel_launch(void* const* d_in, const int* in_sizes, int n_in,
                              void* d_out, int out_size, void* d_ws, size_t ws_size,
                              hipStream_t stream) {
  const float* x     = (const float*)d_in[0];
  const float* w_qkv = (const float*)d_in[1];
  const float* w_out = (const float*)d_in[2];
  const float* b_out = (const float*)d_in[3];
  float* out = (float*)d_out;

  char* ws = (char*)d_ws;
  __bf16* xT    = (__bf16*)(ws);                     // 67,108,864
  __bf16* wqb   = (__bf16*)(ws + 67108864ull);       // 262,144 (k,v rows only)
  __bf16* wqT   = (__bf16*)(ws + 67371008ull);       // 131,072
  __bf16* W2b   = (__bf16*)(ws + 67502080ull);       // 1,048,576
  __bf16* W3    = (__bf16*)(ws + 68550656ull);       // 1,048,576
  float*  S_part= (float*) (ws + 69599232ull);       // 33,554,432
  float*  Zpart = (float*) (ws + 103153664ull);      // 1,048,576
  float*  ctx   = (float*) (ws + 104202240ull);      // 262,144 (end ~99.7 MB)

  conv_w<<<512, 256, 0, stream>>>(w_qkv + 256 * 256, wqb, 512 * 256);
  transpose_wq<<<dim3(8, 8), 256, 0, stream>>>(w_qkv, wqT);
  transpose_x<<<dim3(NPIX / 64, CDIM / 64, BATCH), 256, 0, stream>>>(x, xT);
  gemm256<0><<<dim3(2, NPIX / 128, BATCH), 512, 0, stream>>>(
      wqb, xT, S_part, Zpart, nullptr, nullptr);
  reduce_ctx<<<dim3(4, 64), 256, 0, stream>>>(S_part, Zpart, ctx);
  make_w2<<<dim3(256, BATCH), 256, 0, stream>>>(ctx, w_out, W2b);
  make_w3<<<dim3(2, 2, BATCH), 256, 0, stream>>>(W2b, wqT, W3);
  gemm256<1><<<dim3(NPIX / 128, 1, BATCH), 512, 0, stream>>>(
      W3, xT, nullptr, nullptr, b_out, out);
}

// Round 11
// 177.168 us; speedup vs baseline: 1.5317x; 1.0160x over previous
//
#include <hip/hip_runtime.h>
#include <hip/hip_bf16.h>
#include <cstdint>

#define NPIX 16384   // h*w = 128*128
#define BATCH 8
#define CDIM 256

typedef __bf16 bh8 __attribute__((ext_vector_type(8)));
typedef __bf16 bh4 __attribute__((ext_vector_type(4)));
typedef float  fx4 __attribute__((ext_vector_type(4)));

__device__ __forceinline__ void gload16(const void* g, void* l) {
  __builtin_amdgcn_global_load_lds(
      (const __attribute__((address_space(1))) uint32_t*)g,
      (__attribute__((address_space(3))) uint32_t*)l, 16, 0, 0);
}

__device__ __forceinline__ fx4 mfma16(bh8 a, bh8 b, fx4 c) {
  return __builtin_amdgcn_mfma_f32_16x16x32_bf16(a, b, c, 0, 0, 0);
}

__device__ __forceinline__ void pbar() {
  asm volatile("" ::: "memory");
  __builtin_amdgcn_s_barrier();
  asm volatile("" ::: "memory");
}
#define VMWI(n) asm volatile("s_waitcnt vmcnt(" #n ")" ::: "memory")

// -------- pass 0a: merged weight prep --------------------------------------
// blocks [0,512): w_qkv rows 256..767 f32 -> bf16 (wqb)
// blocks [512,576): WqT[t][o] = Wq[o][t] (first 256 rows) -> bf16
__global__ __launch_bounds__(256) void prep_w(const float* __restrict__ w_qkv,
                                              __bf16* __restrict__ wqb,
                                              __bf16* __restrict__ wqT) {
  __shared__ float tile[32][33];
  int bid = blockIdx.x;
  if (bid < 512) {
    int i = bid * 256 + threadIdx.x;
    wqb[i] = (__bf16)w_qkv[256 * 256 + i];
  } else {
    bid -= 512;
    const int t0 = (bid & 7) * 32, o0 = (bid >> 3) * 32;
    const int tx = threadIdx.x & 31, ty = threadIdx.x >> 5;
#pragma unroll
    for (int j = 0; j < 4; ++j) {
      int r = ty * 4 + j;  // local o
      tile[r][tx] = w_qkv[(size_t)(o0 + r) * 256 + t0 + tx];
    }
    __syncthreads();
#pragma unroll
    for (int j = 0; j < 4; ++j) {
      int tl = ty * 4 + j; // local t
      wqT[(size_t)(t0 + tl) * 256 + o0 + tx] = (__bf16)tile[tx][tl];
    }
  }
}

// -------- pass 0b: x [b][256][NPIX] f32 -> xT [b][NPIX][256] bf16 -----------
// 64c x 64n tiles: 256B-contiguous reads, full-128B-line bh8 writes.
__global__ __launch_bounds__(256) void transpose_x(const float* __restrict__ x,
                                                   __bf16* __restrict__ xT) {
  __shared__ float tf[64][68];
  const int n0 = blockIdx.x * 64, c0 = blockIdx.y * 64, b = blockIdx.z;
  const int u = threadIdx.x;
#pragma unroll
  for (int i = 0; i < 4; ++i) {
    int j = i * 256 + u;
    int r = j >> 4, q = j & 15;  // r: local c, q: px quad
    *(fx4*)&tf[r][q * 4] =
        *(const fx4*)&x[((size_t)b * CDIM + c0 + r) * NPIX + n0 + q * 4];
  }
  __syncthreads();
  const int nl = u >> 2, cq = (u & 3) * 16;
#pragma unroll
  for (int w = 0; w < 2; ++w) {
    bh8 v;
#pragma unroll
    for (int j = 0; j < 8; ++j) v[j] = (__bf16)tf[cq + w * 8 + j][nl];
    *(bh8*)&xT[((size_t)b * NPIX + n0 + nl) * CDIM + c0 + cq + w * 8] = v;
  }
}

// ====== 256x128 tile GEMM, K=256 as 4 x BK=64 (r5-proven schedule) ==========
// EPI==0: A rows = matched k||v for head-group hg; epilogue computes per-head
//         S (32x32 over this block's 128 px) + Z partials in-LDS, then
//         S is bounced through LDS for fully-coalesced fx4 stores.
//         Grid (2,128,8): by=blockIdx.x so the two head-groups sharing a
//         B-tile are adjacent in dispatch order -> same-XCD L2 reuse.
// EPI==1: A = W3[b]; writes f32 out + bias via coalescing LDS bounce.

#define BSP(pb) ((__bf16*)(smem + 32768 + (pb)*16384))

#define STA(kt)                                                                \
  do {                                                                         \
    _Pragma("unroll") for (int i_ = 0; i_ < 4; ++i_) {                         \
      int j_ = i_ * 512 + tid;                                                 \
      int row_ = j_ >> 3, c_ = j_ & 7;                                         \
      int sc_ = c_ ^ (row_ & 7);                                               \
      const __bf16* sb_;                                                       \
      if (EPI == 0) sb_ = (i_ < 2) ? Abk + (size_t)row_ * 256                  \
                                   : Abv + (size_t)(row_ - 128) * 256;         \
      else          sb_ = Ab + (size_t)row_ * 256;                             \
      gload16(sb_ + (kt)*64 + sc_ * 8, As + j_ * 8);                           \
    }                                                                          \
  } while (0)

#define STB(kt, pb)                                                            \
  do {                                                                         \
    _Pragma("unroll") for (int i_ = 0; i_ < 2; ++i_) {                         \
      int j_ = i_ * 512 + tid;                                                 \
      int row_ = j_ >> 3, c_ = j_ & 7;                                         \
      int sc_ = c_ ^ (row_ & 7);                                               \
      gload16(Bb + (size_t)row_ * 256 + (kt)*64 + sc_ * 8, BSP(pb) + j_ * 8);  \
    }                                                                          \
  } while (0)

#define COMP(pb)                                                               \
  do {                                                                         \
    _Pragma("unroll") for (int ks_ = 0; ks_ < 2; ++ks_) {                      \
      bh8 a_[4], b_[4];                                                        \
      const int swk_ = (ks_ * 4 + fq) ^ (fr & 7);                              \
      _Pragma("unroll") for (int m_ = 0; m_ < 4; ++m_)                         \
        a_[m_] = *(const bh8*)&As[(wm * 64 + m_ * 16 + fr) * 64 + swk_ * 8];   \
      _Pragma("unroll") for (int n_ = 0; n_ < 4; ++n_)                         \
        b_[n_] = *(const bh8*)&BSP(pb)[(wn * 64 + n_ * 16 + fr) * 64 + swk_ * 8];\
      _Pragma("unroll") for (int m_ = 0; m_ < 4; ++m_)                         \
      _Pragma("unroll") for (int n_ = 0; n_ < 4; ++n_)                         \
        acc[m_][n_] = mfma16(a_[m_], b_[n_], acc[m_][n_]);                     \
    }                                                                          \
  } while (0)

template <int EPI>
__global__ __launch_bounds__(512, 4) void gemm256(
    const __bf16* __restrict__ A, const __bf16* __restrict__ Bx,
    float* __restrict__ S_part, float* __restrict__ Zpart,
    const float* __restrict__ bias, float* __restrict__ fout) {
  __shared__ __align__(16) char smem[66560];
  __bf16* As = (__bf16*)smem;       // [256 rows][64 k] 32KB
  const int tid = threadIdx.x;
  const int bx = (EPI == 0) ? blockIdx.y : blockIdx.x;
  const int by = (EPI == 0) ? blockIdx.x : blockIdx.y;
  const int b = blockIdx.z;
  const int lane = tid & 63, wid = tid >> 6;
  const int wm = wid >> 1, wn = wid & 1;
  const int fr = lane & 15, fq = lane >> 4;
  const int hg = by * 4;  // EPI==0 head-group
  // wqb holds w_qkv rows 256..767: k at [0,256), v at [256,512)
  const __bf16* Abk = A + (size_t)(hg * 32) * 256;
  const __bf16* Abv = A + (size_t)(256 + hg * 32) * 256;
  const __bf16* Ab  = A + (size_t)b * 65536;
  const __bf16* Bb = Bx + ((size_t)b * NPIX + (size_t)bx * 128) * 256;

  fx4 acc[4][4] = {};

  STB(0, 0); STA(0);
  STB(1, 1); VMWI(2); pbar(); COMP(0); pbar(); STA(1);
  STB(2, 0); VMWI(2); pbar(); COMP(1); pbar(); STA(2);
  STB(3, 1); VMWI(2); pbar(); COMP(0); pbar(); STA(3);
             VMWI(0); pbar(); COMP(1); pbar();

  if (EPI == 0) {
    // ---- epilogue A: bounce exp(k) [128x128] and v [128x128] into LDS
    // (chunk-XOR swizzled), then per-head S = ek·v^T over 128 px + Z rows.
    float* zrow = (float*)(smem + 65536);  // 128 floats
    if (tid < 128) zrow[tid] = 0.f;
#pragma unroll
    for (int m = 0; m < 4; ++m)
#pragma unroll
      for (int n = 0; n < 4; ++n)
#pragma unroll
        for (int j = 0; j < 4; ++j) {
          int r = wm * 64 + m * 16 + fq * 4 + j;   // 0..255 (k then v)
          int px = wn * 64 + n * 16 + fr;          // 0..127
          int pc = px >> 3;
          if (wm < 2) {                            // k rows -> exp -> Lk @0
            int byo = r * 256 + ((pc ^ (r & 7)) << 4) + (px & 7) * 2;
            *(__bf16*)(smem + byo) = (__bf16)__expf(acc[m][n][j]);
          } else {                                 // v rows -> Lv @32768
            int r2 = r - 128;
            int byo = r2 * 256 + ((pc ^ (r2 & 7)) << 4) + (px & 7) * 2;
            *(__bf16*)(smem + 32768 + byo) = (__bf16)acc[m][n][j];
          }
        }
    __syncthreads();
    {  // Z: 4 threads per row, 32 px each
      int r = tid >> 2, c0 = (tid & 3) * 32;
      float za = 0.f;
#pragma unroll
      for (int i2 = 0; i2 < 4; ++i2) {
        int px0 = c0 + i2 * 8;
        int pc = px0 >> 3;
        bh8 ev = *(const bh8*)(smem + r * 256 + ((pc ^ (r & 7)) << 4));
#pragma unroll
        for (int jj = 0; jj < 8; ++jj) za += (float)ev[jj];
      }
      atomicAdd(&zrow[r], za);
    }
    // S: 16 tasks (4 heads x 4 quadrants) over 8 waves, 2 tasks/wave
    fx4 sac0 = {}, sac1 = {};
#pragma unroll
    for (int t2 = 0; t2 < 2; ++t2) {
      int tk = wid * 2 + t2;
      int hl = tk >> 2, quad = tk & 3;
      int drow = (quad >> 1) * 16, erow = (quad & 1) * 16;
      fx4 sac = {};
#pragma unroll
      for (int kt2 = 0; kt2 < 4; ++kt2) {
        int ra = hl * 32 + drow + fr;
        int rb = hl * 32 + erow + fr;
        int pc = kt2 * 4 + fq;
        bh8 af = *(const bh8*)(smem + ra * 256 + ((pc ^ (ra & 7)) << 4));
        bh8 bf = *(const bh8*)(smem + 32768 + rb * 256 + ((pc ^ (rb & 7)) << 4));
        sac = mfma16(af, bf, sac);
      }
      if (t2 == 0) sac0 = sac; else sac1 = sac;
    }
    __syncthreads();  // zrow complete; all Lk/Lv reads done -> smem reusable
    // ---- scatter S into LDS [4 heads][32x32] f32, then coalesced stores
    float* Sb = (float*)smem;  // 16 KB
#pragma unroll
    for (int t2 = 0; t2 < 2; ++t2) {
      int tk = wid * 2 + t2;
      int hl = tk >> 2, quad = tk & 3;
      int drow = (quad >> 1) * 16, erow = (quad & 1) * 16;
      fx4 sv = (t2 == 0) ? sac0 : sac1;
#pragma unroll
      for (int j = 0; j < 4; ++j)
        Sb[hl * 1024 + (drow + fq * 4 + j) * 32 + erow + fr] = sv[j];
    }
    __syncthreads();
    {
      int hl = tid >> 7, idx = tid & 127;
      float* sp = S_part + ((size_t)((b * 8 + hg + hl) * 128 + bx)) * 1024;
      fx4 v0 = *(const fx4*)&Sb[hl * 1024 + idx * 8];
      fx4 v1 = *(const fx4*)&Sb[hl * 1024 + idx * 8 + 4];
      *(fx4*)&sp[idx * 8] = v0;
      *(fx4*)&sp[idx * 8 + 4] = v1;
      if (hl == 0) {  // second pair of heads
        float* sp2 = S_part + ((size_t)((b * 8 + hg + 2 + (idx >> 6)) * 128 + bx)) * 1024;
        (void)sp2;
      }
    }
    // heads 2,3 written by tid 256..511 via hl=tid>>7 in {2,3}? tid>>7 gives 0..3 ✓
    if (tid < 128) {
      int head = hg + (tid >> 5);
      Zpart[((size_t)(b * 8 + head) * 128 + bx) * 32 + (tid & 31)] = zrow[tid];
    }
  } else {
    // ---- epilogue B: per m-slice LDS bounce -> full-line coalesced writes
    const size_t obase = (size_t)b * CDIM * NPIX + (size_t)bx * 128;
    float* Ls = (float*)smem;       // [64][132] pad
#pragma unroll
    for (int m = 0; m < 4; ++m) {
      __syncthreads();
#pragma unroll
      for (int n = 0; n < 4; ++n)
#pragma unroll
        for (int j = 0; j < 4; ++j)
          Ls[(wm * 16 + fq * 4 + j) * 132 + wn * 64 + n * 16 + fr] =
              acc[m][n][j] + bias[wm * 64 + m * 16 + fq * 4 + j];
      __syncthreads();
#pragma unroll
      for (int it = 0; it < 4; ++it) {
        int u = it * 512 + tid;
        int rr = u >> 5, cc = u & 31;
        int gch = (rr >> 4) * 64 + m * 16 + (rr & 15);
        fx4 val = *(const fx4*)&Ls[rr * 132 + cc * 4];
        *(fx4*)&fout[obase + (size_t)gch * NPIX + cc * 4] = val;
      }
    }
  }
}

// -------- pass 2.5: reduce S_part/Zpart over 128 chunks -> ctx --------------
// grid (4 segs, 64 bh): 256 blocks for full-GPU BW.
__global__ __launch_bounds__(256) void reduce_ctx(const float* __restrict__ S_part,
                                                  const float* __restrict__ Zpart,
                                                  float* __restrict__ ctx) {
  const int seg = blockIdx.x;  // 0..3
  const int bh = blockIdx.y;   // 0..63
  const int t = threadIdx.x;
  __shared__ float zs[8];
  if (t < 8) zs[t] = 0.f;
  __syncthreads();
  {
    int row = seg * 8 + (t >> 5);  // global d-row handled by this block
    float z = 0.f;
    for (int ch = (t & 31); ch < 128; ch += 32)
      z += Zpart[((size_t)bh * 128 + ch) * 32 + row];
    atomicAdd(&zs[t >> 5], z);
  }
  __syncthreads();
  const int i = seg * 256 + t;
  float s = 0.f;
  for (int ch = 0; ch < 128; ++ch) s += S_part[((size_t)bh * 128 + ch) * 1024 + i];
  ctx[(size_t)bh * 1024 + i] = s / zs[t >> 5];
}

// -------- pass 3: W2b[b][oc][h*32+d] = sum_e w_out[oc][h*32+e]*ctx ----------
__global__ __launch_bounds__(256) void make_w2(const float* __restrict__ ctx,
                                               const float* __restrict__ w_out,
                                               __bf16* __restrict__ W2b) {
  const int oc = blockIdx.x, b = blockIdx.y, t = threadIdx.x;
  const int h = t >> 5, d = t & 31;
  const float* wrow = w_out + oc * 256 + h * 32;
  const float* crow = ctx + (((size_t)b * 8 + h) * 32 + d) * 32;
  float s = 0.f;
#pragma unroll
  for (int e = 0; e < 32; ++e) s += wrow[e] * crow[e];
  W2b[((size_t)b * 256 + oc) * 256 + t] = (__bf16)s;
}

// -------- pass 3.5: W3[b] = W2b[b] x Wq (via WqT), MFMA ---------------------
__global__ __launch_bounds__(256) void make_w3(const __bf16* __restrict__ W2b,
                                               const __bf16* __restrict__ wqT,
                                               __bf16* __restrict__ W3) {
  const int bx = blockIdx.x, by = blockIdx.y, b = blockIdx.z;
  const int lane = threadIdx.x & 63, wid = threadIdx.x >> 6;
  const int wm = wid >> 1, wn = wid & 1;
  const int fr = lane & 15, fq = lane >> 4;
  const __bf16* Ab = W2b + (size_t)b * 65536 + (size_t)(by * 128 + wm * 64) * 256;
  const __bf16* Bb = wqT + (size_t)(bx * 128 + wn * 64) * 256;
  fx4 acc[4][4] = {};
#pragma unroll
  for (int h = 0; h < 8; ++h) {
    bh8 a_[4], b_[4];
#pragma unroll
    for (int m = 0; m < 4; ++m)
      a_[m] = *(const bh8*)(Ab + (size_t)(m * 16 + fr) * 256 + h * 32 + fq * 8);
#pragma unroll
    for (int n = 0; n < 4; ++n)
      b_[n] = *(const bh8*)(Bb + (size_t)(n * 16 + fr) * 256 + h * 32 + fq * 8);
#pragma unroll
    for (int m = 0; m < 4; ++m)
#pragma unroll
      for (int n = 0; n < 4; ++n) acc[m][n] = mfma16(a_[m], b_[n], acc[m][n]);
  }
#pragma unroll
  for (int m = 0; m < 4; ++m)
#pragma unroll
    for (int n = 0; n < 4; ++n) {
      int r0 = by * 128 + wm * 64 + m * 16 + fq * 4;
      int t0 = bx * 128 + wn * 64 + n * 16 + fr;
#pragma unroll
      for (int j = 0; j < 4; ++j)
        W3[(size_t)b * 65536 + (size_t)(r0 + j) * 256 + t0] = (__bf16)acc[m][n][j];
    }
}

extern "C" void kernel_launch(void* const* d_in, const int* in_sizes, int n_in,
                              void* d_out, int out_size, void* d_ws, size_t ws_size,
                              hipStream_t stream) {
  const float* x     = (const float*)d_in[0];
  const float* w_qkv = (const float*)d_in[1];
  const float* w_out = (const float*)d_in[2];
  const float* b_out = (const float*)d_in[3];
  float* out = (float*)d_out;

  char* ws = (char*)d_ws;
  __bf16* xT    = (__bf16*)(ws);                     // 67,108,864
  __bf16* wqb   = (__bf16*)(ws + 67108864ull);       // 262,144 (k,v rows only)
  __bf16* wqT   = (__bf16*)(ws + 67371008ull);       // 131,072
  __bf16* W2b   = (__bf16*)(ws + 67502080ull);       // 1,048,576
  __bf16* W3    = (__bf16*)(ws + 68550656ull);       // 1,048,576
  float*  S_part= (float*) (ws + 69599232ull);       // 33,554,432
  float*  Zpart = (float*) (ws + 103153664ull);      // 1,048,576
  float*  ctx   = (float*) (ws + 104202240ull);      // 262,144 (end ~99.7 MB)

  prep_w<<<576, 256, 0, stream>>>(w_qkv, wqb, wqT);
  transpose_x<<<dim3(NPIX / 64, CDIM / 64, BATCH), 256, 0, stream>>>(x, xT);
  gemm256<0><<<dim3(2, NPIX / 128, BATCH), 512, 0, stream>>>(
      wqb, xT, S_part, Zpart, nullptr, nullptr);
  reduce_ctx<<<dim3(4, 64), 256, 0, stream>>>(S_part, Zpart, ctx);
  make_w2<<<dim3(256, BATCH), 256, 0, stream>>>(ctx, w_out, W2b);
  make_w3<<<dim3(2, 2, BATCH), 256, 0, stream>>>(W2b, wqT, W3);
  gemm256<1><<<dim3(NPIX / 128, 1, BATCH), 512, 0, stream>>>(
      W3, xT, nullptr, nullptr, b_out, out);
}